// Round 5
// baseline (2422.769 us; speedup 1.0000x reference)
//
#include <hip/hip_runtime.h>
#include <hip/hip_bf16.h>

#define F 128
#define ROWS_PER_BLOCK 80
#define RB 196            // rows per bucket
#define NB_MAX 511        // max buckets (covers nrows <= 100156)
#define HALF_ROWS 98      // rows per agg block (RB/2)
#define BIN_CAP 16        // LDS records per bin (circular)
#define NBLK_BIN 256      // bin_edges grid

// ---------------------------------------------------------------------------
// wx = X @ W.T + b  ->  f32 into d_out  +  bf16 feature-swizzled copy (wxh):
// ushort index r*128 + (j<64 ? 2j : 2(j-64)+1), so a uint32 at [r*64+l]
// holds features (l, l+64) for lane l.
// ---------------------------------------------------------------------------
__global__ __launch_bounds__(256) void gemm_wx_kernel(
    const float* __restrict__ X, const float* __restrict__ W,
    const float* __restrict__ bias, float* __restrict__ wxf,
    __hip_bfloat16* __restrict__ wxh, int nrows)
{
    __shared__ float Wt[F][F];   // 64 KiB
    __shared__ float xs[8][F];   //  4 KiB

    int t = threadIdx.x;
    for (int idx = t; idx < F * F; idx += 256) {
        int j = idx >> 7, k = idx & (F - 1);
        Wt[k][j] = W[idx];
    }
    __syncthreads();

    int j  = t & (F - 1);
    int rg = t >> 7;
    float bj = bias[j];
    int swz = (j < 64) ? (2 * j) : (2 * (j - 64) + 1);
    long base = (long)blockIdx.x * ROWS_PER_BLOCK;

    for (int r0 = 0; r0 < ROWS_PER_BLOCK; r0 += 8) {
        long row0 = base + r0;
        __syncthreads();
        for (int idx = t; idx < 8 * F; idx += 256) {
            int rr = idx >> 7, kk = idx & (F - 1);
            long rowi = row0 + rr;
            xs[rr][kk] = (rowi < nrows) ? X[rowi * F + kk] : 0.0f;
        }
        __syncthreads();

        float acc0 = 0.f, acc1 = 0.f, acc2 = 0.f, acc3 = 0.f;
#pragma unroll 4
        for (int k = 0; k < F; ++k) {
            float w = Wt[k][j];
            acc0 += xs[rg * 4 + 0][k] * w;
            acc1 += xs[rg * 4 + 1][k] * w;
            acc2 += xs[rg * 4 + 2][k] * w;
            acc3 += xs[rg * 4 + 3][k] * w;
        }

        float acc[4] = {acc0, acc1, acc2, acc3};
#pragma unroll
        for (int r = 0; r < 4; ++r) {
            long rowi = row0 + rg * 4 + r;
            if (rowi < nrows) {
                float v = acc[r] + bj;
                wxf[rowi * F + j] = v;
                wxh[rowi * F + swz] = __float2bfloat16(v);
            }
        }
    }
}

// ---------------------------------------------------------------------------
// Counting-bin with LDS write-combining. Each block: 511 bins x 16 records.
// Full 8-record (64B) chunks flushed via per-bucket cursor -> full-line
// global writes, densely packed (no padding). Record = (rl<<17|c, v^2),
// diagonal edges stored with v^2=0 (harmless in aggregation).
// ---------------------------------------------------------------------------
__global__ __launch_bounds__(256) void bin_edges_kernel(
    const int* __restrict__ rowi, const int* __restrict__ coli,
    const float* __restrict__ ev, int* __restrict__ cur,
    int2* __restrict__ arena, int E, int NB, int CAP)
{
    __shared__ int2 bins[NB_MAX][BIN_CAP];   // 65,408 B
    __shared__ int  cnt[NB_MAX];             //  2,044 B
    __shared__ int  flushed[NB_MAX];         //  2,044 B

    int t = threadIdx.x;
    for (int i = t; i < NB; i += 256) { cnt[i] = 0; flushed[i] = 0; }
    __syncthreads();

    long per   = ((long)E + NBLK_BIN - 1) / NBLK_BIN;
    long start = (long)blockIdx.x * per;
    long endE  = start + per; if (endE > E) endE = E;

    for (long base = start; base < endE; base += 256) {
        long i = base + t;
        if (i < endE) {
            int r = rowi[i];
            int c = coli[i];
            float v = ev[i];
            float v2 = (r != c) ? v * v : 0.0f;
            int b  = r / RB;                       // const-div -> magic mul
            int rl = r - b * RB;                   // 0..195
            int pos = atomicAdd(&cnt[b], 1);
            bins[b][pos & (BIN_CAP - 1)] = make_int2((rl << 17) | c, __float_as_int(v2));
        }
        __syncthreads();
        // flush phase: thread t owns bins t, t+256
        for (int bb = t; bb < NB; bb += 256) {
            while (cnt[bb] - flushed[bb] >= 8) {
                int gpos = atomicAdd(&cur[bb], 8);
                if (gpos + 8 <= CAP) {
                    const int2* src = &bins[bb][flushed[bb] & (BIN_CAP - 1)];
                    int2* dst = &arena[(size_t)bb * CAP + gpos];
                    if ((gpos & 1) == 0) {
                        const int4* s4 = (const int4*)src;
                        int4* d4 = (int4*)dst;
                        d4[0] = s4[0]; d4[1] = s4[1]; d4[2] = s4[2]; d4[3] = s4[3];
                    } else {
#pragma unroll
                        for (int k = 0; k < 8; ++k) dst[k] = src[k];
                    }
                }
                flushed[bb] += 8;
            }
        }
        __syncthreads();
    }
    // final flush: dense (no padding)
    for (int bb = t; bb < NB; bb += 256) {
        int rem = cnt[bb] - flushed[bb];
        if (rem > 0) {
            int gpos = atomicAdd(&cur[bb], rem);
            if (gpos + rem <= CAP) {
                int2* dst = &arena[(size_t)bb * CAP + gpos];
                for (int k = 0; k < rem; ++k)
                    dst[k] = bins[bb][(flushed[bb] + k) & (BIN_CAP - 1)];
            }
        }
    }
}

// ---------------------------------------------------------------------------
// Aggregate per (bucket, row-half): acc[98][128] f32 in LDS (50KB -> 2
// blocks/CU). Stream bucket records (uniform loads), gather wxh row (256B
// contiguous, lane l gets features (l, l+64)), ds_add_f32 into acc
// (2-way bank aliasing = free). Fused finalize: out = wx * acc, wx read
// from d_out (written by gemm) and overwritten in place.
// ---------------------------------------------------------------------------
__global__ __launch_bounds__(256) void agg_kernel(
    const int* __restrict__ cur, const int2* __restrict__ arena,
    const unsigned int* __restrict__ wxh32, float* __restrict__ outwx,
    int nrows, int CAP)
{
    __shared__ float acc[HALF_ROWS * F];   // 50,176 B

    int b = blockIdx.x >> 1;
    int h = blockIdx.x & 1;
    int row0 = b * RB + h * HALF_ROWS;
    int nr = nrows - row0;
    if (nr > HALF_ROWS) nr = HALF_ROWS;

    for (int i = threadIdx.x; i < HALF_ROWS * F; i += 256) acc[i] = 0.f;
    __syncthreads();

    if (nr > 0) {
        int nrec = cur[b]; if (nrec > CAP) nrec = CAP;
        int wave = threadIdx.x >> 6;
        int lane = threadIdx.x & 63;
        int rlo = h * HALF_ROWS;
        int rhi = rlo + nr;
        const int2* recs = arena + (size_t)b * CAP;

        // 4 records per wave-iteration for MLP depth
        for (int i0 = wave * 4; i0 < nrec; i0 += 16) {
            int2 r4[4];
#pragma unroll
            for (int k = 0; k < 4; ++k) {
                int idx = i0 + k;
                r4[k] = (idx < nrec) ? recs[idx] : make_int2(0x0FFE0000, 0); // rl=511 -> skip
            }
#pragma unroll
            for (int k = 0; k < 4; ++k) {
                int rl = r4[k].x >> 17;
                if (rl >= rlo && rl < rhi) {
                    int c = r4[k].x & 0x1FFFF;
                    float v2 = __int_as_float(r4[k].y);
                    unsigned int g = wxh32[(size_t)c * 64 + lane];
                    float flo = __uint_as_float(g << 16);
                    float fhi = __uint_as_float(g & 0xFFFF0000u);
                    int rr = rl - rlo;
                    atomicAdd(&acc[rr * F + lane], v2 * flo);
                    atomicAdd(&acc[rr * F + lane + 64], v2 * fhi);
                }
            }
        }
    }
    __syncthreads();

    for (int i = threadIdx.x; i < nr * F; i += 256) {
        int rr = i >> 7, j = i & 127;
        size_t o = (size_t)(row0 + rr) * F + j;
        outwx[o] = outwx[o] * acc[rr * F + j];
    }
}

// ---------------------------------------------------------------------------
// Last-resort fallback (round-1, proven): atomic scatter + finalize
// ---------------------------------------------------------------------------
__global__ __launch_bounds__(256) void edge_scatter_kernel(
    const int* __restrict__ rowi, const int* __restrict__ coli,
    const float* __restrict__ ev, const float* __restrict__ wx,
    float* __restrict__ temp, int E)
{
    int tid = blockIdx.x * 256 + threadIdx.x;
    int e   = tid >> 5;
    if (e >= E) return;
    int lane = tid & 31;
    int r = rowi[e];
    int c = coli[e];
    if (r == c) return;
    float v = ev[e];
    v = v * v;
    const float4 wv = *reinterpret_cast<const float4*>(wx + (size_t)c * F + lane * 4);
    float* tp = temp + (size_t)r * F + lane * 4;
    atomicAdd(tp + 0, v * wv.x);
    atomicAdd(tp + 1, v * wv.y);
    atomicAdd(tp + 2, v * wv.z);
    atomicAdd(tp + 3, v * wv.w);
}

__global__ __launch_bounds__(256) void finalize_kernel(
    float* __restrict__ out, const float* __restrict__ temp, int n4)
{
    int i = blockIdx.x * 256 + threadIdx.x;
    if (i >= n4) return;
    float4 o  = reinterpret_cast<float4*>(out)[i];
    float4 tv = reinterpret_cast<const float4*>(temp)[i];
    o.x *= tv.x; o.y *= tv.y; o.z *= tv.z; o.w *= tv.w;
    reinterpret_cast<float4*>(out)[i] = o;
}

// (dummy kernel name kept for harness identification)
__global__ void Interaction_GraphConvolution_55963423867450_kernel() {}

extern "C" void kernel_launch(void* const* d_in, const int* in_sizes, int n_in,
                              void* d_out, int out_size, void* d_ws, size_t ws_size,
                              hipStream_t stream)
{
    const float* X  = (const float*)d_in[0];
    const int*   ei = (const int*)d_in[1];   // [2, E] int32
    const float* ev = (const float*)d_in[2];
    const float* W  = (const float*)d_in[3];
    const float* b  = (const float*)d_in[4];
    float* out = (float*)d_out;

    int nrows = in_sizes[0] / F;
    int E     = in_sizes[2];
    const int* rowi = ei;
    const int* coli = ei + E;

    int gblocks = (nrows + ROWS_PER_BLOCK - 1) / ROWS_PER_BLOCK;

    int NB = (nrows + RB - 1) / RB;
    if (NB <= NB_MAX) {
        // CAP: avg records/bucket * 1.25 + 512, rounded to multiple of 8
        long avg = (long)E / NB;
        int CAP = (int)(((avg * 5) / 4 + 512 + 7) & ~7L);

        char* p = (char*)d_ws;
        __hip_bfloat16* wxh = (__hip_bfloat16*)p;
        p += (size_t)nrows * F * sizeof(__hip_bfloat16);
        int* cur = (int*)p;
        p += (size_t)((NB + 3) & ~3) * sizeof(int);
        p = (char*)(((uintptr_t)p + 63) & ~(uintptr_t)63);
        int2* arena = (int2*)p;
        p += (size_t)NB * CAP * sizeof(int2);
        size_t need = (size_t)(p - (char*)d_ws);

        if (ws_size >= need) {
            hipMemsetAsync(cur, 0, (size_t)NB * sizeof(int), stream);
            gemm_wx_kernel<<<gblocks, 256, 0, stream>>>(X, W, b, out, wxh, nrows);
            bin_edges_kernel<<<NBLK_BIN, 256, 0, stream>>>(rowi, coli, ev, cur,
                                                           arena, E, NB, CAP);
            agg_kernel<<<NB * 2, 256, 0, stream>>>(cur, arena,
                                                   (const unsigned int*)wxh,
                                                   out, nrows, CAP);
            return;
        }
    }

    // ---------- last resort: atomic scatter (round-1) ----------
    float* temp = (float*)d_ws;   // [nrows, 128]
    hipMemsetAsync(temp, 0, (size_t)nrows * F * sizeof(float), stream);
    __hip_bfloat16* wxh_dummy = (__hip_bfloat16*)((char*)d_ws + (size_t)nrows * F * sizeof(float));
    // fallback requires ws >= 76.8MB for temp+wxh; wxh write is harmless scratch
    gemm_wx_kernel<<<gblocks, 256, 0, stream>>>(X, W, b, out, wxh_dummy, nrows);
    long ethreads = (long)E * 32;
    int  eblocks32 = (int)((ethreads + 255) / 256);
    edge_scatter_kernel<<<eblocks32, 256, 0, stream>>>(rowi, coli, ev, out, temp, E);
    int n4 = nrows * F / 4;
    finalize_kernel<<<(n4 + 255) / 256, 256, 0, stream>>>(out, temp, n4);
}

// Round 6
// 482.080 us; speedup vs baseline: 5.0257x; 5.0257x over previous
//
#include <hip/hip_runtime.h>
#include <hip/hip_bf16.h>

#define F 128
#define ROWS_PER_BLOCK 80
#define RB 196            // rows per bucket
#define NB_MAX 511        // max buckets (nrows <= 100156)
#define BIN_CAP 16        // LDS records per bin (circular)
#define NBLK_BIN 256      // bin_edges grid

// ---------------------------------------------------------------------------
// wx = X @ W.T + b  ->  f32 into d_out (wxf)  +  plain row-major bf16 (wxh)
// ---------------------------------------------------------------------------
__global__ __launch_bounds__(256) void gemm_wx_kernel(
    const float* __restrict__ X, const float* __restrict__ W,
    const float* __restrict__ bias, float* __restrict__ wxf,
    __hip_bfloat16* __restrict__ wxh, int nrows)
{
    __shared__ float Wt[F][F];   // 64 KiB
    __shared__ float xs[8][F];   //  4 KiB

    int t = threadIdx.x;
    for (int idx = t; idx < F * F; idx += 256) {
        int j = idx >> 7, k = idx & (F - 1);
        Wt[k][j] = W[idx];
    }
    __syncthreads();

    int j  = t & (F - 1);
    int rg = t >> 7;
    float bj = bias[j];
    long base = (long)blockIdx.x * ROWS_PER_BLOCK;

    for (int r0 = 0; r0 < ROWS_PER_BLOCK; r0 += 8) {
        long row0 = base + r0;
        __syncthreads();
        for (int idx = t; idx < 8 * F; idx += 256) {
            int rr = idx >> 7, kk = idx & (F - 1);
            long rowi = row0 + rr;
            xs[rr][kk] = (rowi < nrows) ? X[rowi * F + kk] : 0.0f;
        }
        __syncthreads();

        float acc0 = 0.f, acc1 = 0.f, acc2 = 0.f, acc3 = 0.f;
#pragma unroll 4
        for (int k = 0; k < F; ++k) {
            float w = Wt[k][j];
            acc0 += xs[rg * 4 + 0][k] * w;
            acc1 += xs[rg * 4 + 1][k] * w;
            acc2 += xs[rg * 4 + 2][k] * w;
            acc3 += xs[rg * 4 + 3][k] * w;
        }

        float acc[4] = {acc0, acc1, acc2, acc3};
#pragma unroll
        for (int r = 0; r < 4; ++r) {
            long rowi = row0 + rg * 4 + r;
            if (rowi < nrows) {
                float v = acc[r] + bj;
                wxf[rowi * F + j] = v;
                wxh[rowi * F + j] = __float2bfloat16(v);
            }
        }
    }
}

// ---------------------------------------------------------------------------
// Counting-bin with LDS write-combining (proven round 5): 511 bins x 16 recs,
// full 64B chunks flushed via per-bucket cursor -> coalesced dense arena.
// Record = (rl<<17 | c, v^2); diagonal edges carry v^2 = 0.
// ---------------------------------------------------------------------------
__global__ __launch_bounds__(256) void bin_edges_kernel(
    const int* __restrict__ rowi, const int* __restrict__ coli,
    const float* __restrict__ ev, int* __restrict__ cur,
    int2* __restrict__ arena, int E, int NB, int CAP)
{
    __shared__ int2 bins[NB_MAX][BIN_CAP];
    __shared__ int  cnt[NB_MAX];
    __shared__ int  flushed[NB_MAX];

    int t = threadIdx.x;
    for (int i = t; i < NB; i += 256) { cnt[i] = 0; flushed[i] = 0; }
    __syncthreads();

    long per   = ((long)E + NBLK_BIN - 1) / NBLK_BIN;
    long start = (long)blockIdx.x * per;
    long endE  = start + per; if (endE > E) endE = E;

    for (long base = start; base < endE; base += 256) {
        long i = base + t;
        if (i < endE) {
            int r = rowi[i];
            int c = coli[i];
            float v = ev[i];
            float v2 = (r != c) ? v * v : 0.0f;
            int b  = r / RB;
            int rl = r - b * RB;
            int pos = atomicAdd(&cnt[b], 1);
            bins[b][pos & (BIN_CAP - 1)] = make_int2((rl << 17) | c, __float_as_int(v2));
        }
        __syncthreads();
        for (int bb = t; bb < NB; bb += 256) {
            while (cnt[bb] - flushed[bb] >= 8) {
                int gpos = atomicAdd(&cur[bb], 8);
                if (gpos + 8 <= CAP) {
                    const int2* src = &bins[bb][flushed[bb] & (BIN_CAP - 1)];
                    int2* dst = &arena[(size_t)bb * CAP + gpos];
                    if ((gpos & 1) == 0) {
                        const int4* s4 = (const int4*)src;
                        int4* d4 = (int4*)dst;
                        d4[0] = s4[0]; d4[1] = s4[1]; d4[2] = s4[2]; d4[3] = s4[3];
                    } else {
#pragma unroll
                        for (int k = 0; k < 8; ++k) dst[k] = src[k];
                    }
                }
                flushed[bb] += 8;
            }
        }
        __syncthreads();
    }
    for (int bb = t; bb < NB; bb += 256) {
        int rem = cnt[bb] - flushed[bb];
        if (rem > 0) {
            int gpos = atomicAdd(&cur[bb], rem);
            if (gpos + rem <= CAP) {
                int2* dst = &arena[(size_t)bb * CAP + gpos];
                for (int k = 0; k < rem; ++k)
                    dst[k] = bins[bb][(flushed[bb] + k) & (BIN_CAP - 1)];
            }
        }
    }
}

// ---------------------------------------------------------------------------
// Bucket-local counting sort: block = bucket. Count per-row (LDS), scan,
// scatter into per-row-ordered arena2; emit rowoff = (start,end) absolute.
// All record traffic confined to the bucket's ~67KB L2-hot window.
// ---------------------------------------------------------------------------
__global__ __launch_bounds__(256) void sort_bucket_kernel(
    const int* __restrict__ cur, const int2* __restrict__ arena,
    int2* __restrict__ arena2, int2* __restrict__ rowoff,
    int nrows, int CAP)
{
    __shared__ int rcnt[RB];
    __shared__ int rcur[RB];
    __shared__ int sscan[256];

    int b = blockIdx.x;
    int t = threadIdx.x;
    int nrec = cur[b]; if (nrec > CAP) nrec = CAP;
    const int2* src = arena  + (size_t)b * CAP;
    int2*       dst = arena2 + (size_t)b * CAP;

    for (int i = t; i < RB; i += 256) rcnt[i] = 0;
    __syncthreads();

    for (int i = t; i < nrec; i += 256)
        atomicAdd(&rcnt[src[i].x >> 17], 1);
    __syncthreads();

    int v = (t < RB) ? rcnt[t] : 0;
    sscan[t] = v;
    __syncthreads();
#pragma unroll
    for (int d = 1; d < 256; d <<= 1) {
        int u = (t >= d) ? sscan[t - d] : 0;
        __syncthreads();
        sscan[t] += u;
        __syncthreads();
    }
    if (t < RB) {
        int start = sscan[t] - v;
        rcur[t] = start;
        int grow = b * RB + t;
        if (grow < nrows)
            rowoff[grow] = make_int2(b * CAP + start, b * CAP + start + v);
    }
    __syncthreads();

    for (int i = t; i < nrec; i += 256) {
        int2 rec = src[i];
        int pos = atomicAdd(&rcur[rec.x >> 17], 1);
        dst[pos] = rec;
    }
}

// ---------------------------------------------------------------------------
// One wave per row, branch-free 4-deep unrolled bf16 gather, register acc,
// fused finalize: out[r] = wx[r] * acc  (wx f32 lives in d_out, in-place).
// ---------------------------------------------------------------------------
__global__ __launch_bounds__(256) void agg_row_kernel(
    const int2* __restrict__ rowoff, const int2* __restrict__ arena2,
    const unsigned int* __restrict__ wxh32, float* __restrict__ outwx,
    int nrows)
{
    int wid  = (blockIdx.x * 256 + threadIdx.x) >> 6;
    int lane = threadIdx.x & 63;
    if (wid >= nrows) return;

    int2 se   = rowoff[wid];
    int start = __builtin_amdgcn_readfirstlane(se.x);
    int end   = __builtin_amdgcn_readfirstlane(se.y);

    float accx = 0.f, accy = 0.f;
    int e = start;
    for (; e + 3 < end; e += 4) {
        int2 r0 = arena2[e];
        int2 r1 = arena2[e + 1];
        int2 r2 = arena2[e + 2];
        int2 r3 = arena2[e + 3];
        unsigned int g0 = wxh32[(size_t)(r0.x & 0x1FFFF) * 64 + lane];
        unsigned int g1 = wxh32[(size_t)(r1.x & 0x1FFFF) * 64 + lane];
        unsigned int g2 = wxh32[(size_t)(r2.x & 0x1FFFF) * 64 + lane];
        unsigned int g3 = wxh32[(size_t)(r3.x & 0x1FFFF) * 64 + lane];
        float v0 = __int_as_float(r0.y), v1 = __int_as_float(r1.y);
        float v2 = __int_as_float(r2.y), v3 = __int_as_float(r3.y);
        accx = fmaf(v0, __uint_as_float(g0 << 16), accx);
        accy = fmaf(v0, __uint_as_float(g0 & 0xFFFF0000u), accy);
        accx = fmaf(v1, __uint_as_float(g1 << 16), accx);
        accy = fmaf(v1, __uint_as_float(g1 & 0xFFFF0000u), accy);
        accx = fmaf(v2, __uint_as_float(g2 << 16), accx);
        accy = fmaf(v2, __uint_as_float(g2 & 0xFFFF0000u), accy);
        accx = fmaf(v3, __uint_as_float(g3 << 16), accx);
        accy = fmaf(v3, __uint_as_float(g3 & 0xFFFF0000u), accy);
    }
    for (; e < end; ++e) {
        int2 r0 = arena2[e];
        unsigned int g0 = wxh32[(size_t)(r0.x & 0x1FFFF) * 64 + lane];
        float v0 = __int_as_float(r0.y);
        accx = fmaf(v0, __uint_as_float(g0 << 16), accx);
        accy = fmaf(v0, __uint_as_float(g0 & 0xFFFF0000u), accy);
    }

    float2 wr = *reinterpret_cast<const float2*>(outwx + (size_t)wid * F + lane * 2);
    float2 o;
    o.x = wr.x * accx;
    o.y = wr.y * accy;
    *reinterpret_cast<float2*>(outwx + (size_t)wid * F + lane * 2) = o;
}

// ---------------------------------------------------------------------------
// Last-resort fallback (round-1, proven): atomic scatter + finalize
// ---------------------------------------------------------------------------
__global__ __launch_bounds__(256) void edge_scatter_kernel(
    const int* __restrict__ rowi, const int* __restrict__ coli,
    const float* __restrict__ ev, const float* __restrict__ wx,
    float* __restrict__ temp, int E)
{
    int tid = blockIdx.x * 256 + threadIdx.x;
    int e   = tid >> 5;
    if (e >= E) return;
    int lane = tid & 31;
    int r = rowi[e];
    int c = coli[e];
    if (r == c) return;
    float v = ev[e];
    v = v * v;
    const float4 wv = *reinterpret_cast<const float4*>(wx + (size_t)c * F + lane * 4);
    float* tp = temp + (size_t)r * F + lane * 4;
    atomicAdd(tp + 0, v * wv.x);
    atomicAdd(tp + 1, v * wv.y);
    atomicAdd(tp + 2, v * wv.z);
    atomicAdd(tp + 3, v * wv.w);
}

__global__ __launch_bounds__(256) void finalize_kernel(
    float* __restrict__ out, const float* __restrict__ temp, int n4)
{
    int i = blockIdx.x * 256 + threadIdx.x;
    if (i >= n4) return;
    float4 o  = reinterpret_cast<float4*>(out)[i];
    float4 tv = reinterpret_cast<const float4*>(temp)[i];
    o.x *= tv.x; o.y *= tv.y; o.z *= tv.z; o.w *= tv.w;
    reinterpret_cast<float4*>(out)[i] = o;
}

__global__ void Interaction_GraphConvolution_55963423867450_kernel() {}

extern "C" void kernel_launch(void* const* d_in, const int* in_sizes, int n_in,
                              void* d_out, int out_size, void* d_ws, size_t ws_size,
                              hipStream_t stream)
{
    const float* X  = (const float*)d_in[0];
    const int*   ei = (const int*)d_in[1];   // [2, E] int32
    const float* ev = (const float*)d_in[2];
    const float* W  = (const float*)d_in[3];
    const float* b  = (const float*)d_in[4];
    float* out = (float*)d_out;

    int nrows = in_sizes[0] / F;
    int E     = in_sizes[2];
    const int* rowi = ei;
    const int* coli = ei + E;

    int gblocks = (nrows + ROWS_PER_BLOCK - 1) / ROWS_PER_BLOCK;

    int NB = (nrows + RB - 1) / RB;
    if (NB <= NB_MAX) {
        long avg = (long)E / NB;
        int CAP = (int)(((avg * 5) / 4 + 512 + 7) & ~7L);

        char* p = (char*)d_ws;
        __hip_bfloat16* wxh = (__hip_bfloat16*)p;
        p += (size_t)nrows * F * sizeof(__hip_bfloat16);
        int* cur = (int*)p;
        p += (size_t)((NB + 3) & ~3) * sizeof(int);
        p = (char*)(((uintptr_t)p + 63) & ~(uintptr_t)63);
        int2* rowoff = (int2*)p;
        p += (size_t)nrows * sizeof(int2);
        int2* arena = (int2*)p;
        p += (size_t)NB * CAP * sizeof(int2);
        int2* arena2 = (int2*)p;
        p += (size_t)NB * CAP * sizeof(int2);
        size_t need = (size_t)(p - (char*)d_ws);

        if (ws_size >= need) {
            hipMemsetAsync(cur, 0, (size_t)NB * sizeof(int), stream);
            gemm_wx_kernel<<<gblocks, 256, 0, stream>>>(X, W, b, out, wxh, nrows);
            bin_edges_kernel<<<NBLK_BIN, 256, 0, stream>>>(rowi, coli, ev, cur,
                                                           arena, E, NB, CAP);
            sort_bucket_kernel<<<NB, 256, 0, stream>>>(cur, arena, arena2,
                                                       rowoff, nrows, CAP);
            int ablocks = (int)(((long)nrows * 64 + 255) / 256);
            agg_row_kernel<<<ablocks, 256, 0, stream>>>(rowoff, arena2,
                                                        (const unsigned int*)wxh,
                                                        out, nrows);
            return;
        }
    }

    // ---------- last resort: atomic scatter (round-1) ----------
    float* temp = (float*)d_ws;   // [nrows, 128]
    hipMemsetAsync(temp, 0, (size_t)nrows * F * sizeof(float), stream);
    __hip_bfloat16* wxh_dummy = (__hip_bfloat16*)((char*)d_ws + (size_t)nrows * F * sizeof(float));
    gemm_wx_kernel<<<gblocks, 256, 0, stream>>>(X, W, b, out, wxh_dummy, nrows);
    long ethreads = (long)E * 32;
    int  eblocks32 = (int)((ethreads + 255) / 256);
    edge_scatter_kernel<<<eblocks32, 256, 0, stream>>>(rowi, coli, ev, out, temp, E);
    int n4 = nrows * F / 4;
    finalize_kernel<<<(n4 + 255) / 256, 256, 0, stream>>>(out, temp, n4);
}

// Round 7
// 332.552 us; speedup vs baseline: 7.2854x; 1.4496x over previous
//
#include <hip/hip_runtime.h>
#include <hip/hip_bf16.h>

#define F 128
#define RB 196            // rows per bucket
#define NB_MAX 511        // max buckets (nrows <= 100156)
#define BIN_CAP 16        // LDS records per bin (circular)
#define NBLK_BIN 256      // bin_edges grid

typedef __attribute__((ext_vector_type(8))) short bf16x8;
typedef __attribute__((ext_vector_type(4))) float f32x4;

static __device__ __forceinline__ short f2bf(float f) {
    __hip_bfloat16 h = __float2bfloat16(f);
    return __builtin_bit_cast(short, h);
}

// ---------------------------------------------------------------------------
// MFMA GEMM: wx = X @ W.T + b. Block = 128 rows x 128 cols, K=128 whole.
// LDS tiles padded to 136 shorts/row -> ds_read_b128 conflict-free.
// Outputs: f32 wx -> wxf (d_out), bf16 wx -> wxh (ws, for gathers).
// Fragment layouts (guide §3, m89/m91): A row=l&15 k=(l>>4)*8+j;
// B col=l&15 same k; D col=l&15 row=(l>>4)*4+reg.
// ---------------------------------------------------------------------------
__global__ __launch_bounds__(256) void gemm_mfma_kernel(
    const float* __restrict__ X, const float* __restrict__ W,
    const float* __restrict__ bias, float* __restrict__ wxf,
    __hip_bfloat16* __restrict__ wxh, int nrows)
{
    __shared__ short xs[128][136];   // 34,816 B
    __shared__ short wt[128][136];   // 34,816 B
    __shared__ float bsh[128];       //     512 B

    int t = threadIdx.x;
    long row0 = (long)blockIdx.x * 128;

    // stage W (bf16) + bias
    {
        int r = t >> 1, h = t & 1;
        const float4* src = reinterpret_cast<const float4*>(W + r * F + h * 64);
#pragma unroll
        for (int i = 0; i < 16; ++i) {
            float4 v = src[i];
            short4 s;
            s.x = f2bf(v.x); s.y = f2bf(v.y); s.z = f2bf(v.z); s.w = f2bf(v.w);
            *reinterpret_cast<short4*>(&wt[r][h * 64 + i * 4]) = s;
        }
        if (t < 128) bsh[t] = bias[t];
    }
    // stage X (clamp OOB rows to a valid row; their results are discarded)
    {
        int r = t >> 1, h = t & 1;
        long gr = row0 + r; if (gr > nrows - 1) gr = nrows - 1;
        const float4* src = reinterpret_cast<const float4*>(X + gr * F + h * 64);
#pragma unroll
        for (int i = 0; i < 16; ++i) {
            float4 v = src[i];
            short4 s;
            s.x = f2bf(v.x); s.y = f2bf(v.y); s.z = f2bf(v.z); s.w = f2bf(v.w);
            *reinterpret_cast<short4*>(&xs[r][h * 64 + i * 4]) = s;
        }
    }
    __syncthreads();

    int wave = t >> 6, lane = t & 63;
    int l15 = lane & 15, lg = lane >> 4;
    int mrow = wave * 32;

    float bj[8];
#pragma unroll
    for (int nf = 0; nf < 8; ++nf) bj[nf] = bsh[nf * 16 + l15];

    f32x4 acc[2][8] = {};

#pragma unroll
    for (int ks = 0; ks < 4; ++ks) {
        bf16x8 a0 = *reinterpret_cast<const bf16x8*>(&xs[mrow + l15][ks * 32 + lg * 8]);
        bf16x8 a1 = *reinterpret_cast<const bf16x8*>(&xs[mrow + 16 + l15][ks * 32 + lg * 8]);
#pragma unroll
        for (int nf = 0; nf < 8; ++nf) {
            bf16x8 bfr = *reinterpret_cast<const bf16x8*>(&wt[nf * 16 + l15][ks * 32 + lg * 8]);
            acc[0][nf] = __builtin_amdgcn_mfma_f32_16x16x32_bf16(a0, bfr, acc[0][nf], 0, 0, 0);
            acc[1][nf] = __builtin_amdgcn_mfma_f32_16x16x32_bf16(a1, bfr, acc[1][nf], 0, 0, 0);
        }
    }

#pragma unroll
    for (int mf = 0; mf < 2; ++mf) {
#pragma unroll
        for (int i = 0; i < 4; ++i) {
            long grow = row0 + mrow + mf * 16 + lg * 4 + i;
            if (grow < nrows) {
#pragma unroll
                for (int nf = 0; nf < 8; ++nf) {
                    float v = acc[mf][nf][i] + bj[nf];
                    int col = nf * 16 + l15;
                    wxf[grow * F + col] = v;
                    wxh[grow * F + col] = __float2bfloat16(v);
                }
            }
        }
    }
}

// ---------------------------------------------------------------------------
// Counting-bin with LDS write-combining (proven): 511 bins x 16 recs,
// full 64B chunks flushed via per-bucket cursor -> coalesced dense arena.
// Record = (rl<<17 | c, v^2); diagonal edges carry v^2 = 0.
// ---------------------------------------------------------------------------
__global__ __launch_bounds__(256) void bin_edges_kernel(
    const int* __restrict__ rowi, const int* __restrict__ coli,
    const float* __restrict__ ev, int* __restrict__ cur,
    int2* __restrict__ arena, int E, int NB, int CAP)
{
    __shared__ int2 bins[NB_MAX][BIN_CAP];
    __shared__ int  cnt[NB_MAX];
    __shared__ int  flushed[NB_MAX];

    int t = threadIdx.x;
    for (int i = t; i < NB; i += 256) { cnt[i] = 0; flushed[i] = 0; }
    __syncthreads();

    long per   = ((long)E + NBLK_BIN - 1) / NBLK_BIN;
    long start = (long)blockIdx.x * per;
    long endE  = start + per; if (endE > E) endE = E;

    for (long base = start; base < endE; base += 256) {
        long i = base + t;
        if (i < endE) {
            int r = rowi[i];
            int c = coli[i];
            float v = ev[i];
            float v2 = (r != c) ? v * v : 0.0f;
            int b  = r / RB;
            int rl = r - b * RB;
            int pos = atomicAdd(&cnt[b], 1);
            bins[b][pos & (BIN_CAP - 1)] = make_int2((rl << 17) | c, __float_as_int(v2));
        }
        __syncthreads();
        for (int bb = t; bb < NB; bb += 256) {
            while (cnt[bb] - flushed[bb] >= 8) {
                int gpos = atomicAdd(&cur[bb], 8);
                if (gpos + 8 <= CAP) {
                    const int2* src = &bins[bb][flushed[bb] & (BIN_CAP - 1)];
                    int2* dst = &arena[(size_t)bb * CAP + gpos];
                    if ((gpos & 1) == 0) {
                        const int4* s4 = (const int4*)src;
                        int4* d4 = (int4*)dst;
                        d4[0] = s4[0]; d4[1] = s4[1]; d4[2] = s4[2]; d4[3] = s4[3];
                    } else {
#pragma unroll
                        for (int k = 0; k < 8; ++k) dst[k] = src[k];
                    }
                }
                flushed[bb] += 8;
            }
        }
        __syncthreads();
    }
    for (int bb = t; bb < NB; bb += 256) {
        int rem = cnt[bb] - flushed[bb];
        if (rem > 0) {
            int gpos = atomicAdd(&cur[bb], rem);
            if (gpos + rem <= CAP) {
                int2* dst = &arena[(size_t)bb * CAP + gpos];
                for (int k = 0; k < rem; ++k)
                    dst[k] = bins[bb][(flushed[bb] + k) & (BIN_CAP - 1)];
            }
        }
    }
}

// ---------------------------------------------------------------------------
// Bucket-local counting sort (proven): per-row order within bucket.
// ---------------------------------------------------------------------------
__global__ __launch_bounds__(256) void sort_bucket_kernel(
    const int* __restrict__ cur, const int2* __restrict__ arena,
    int2* __restrict__ arena2, int2* __restrict__ rowoff,
    int nrows, int CAP)
{
    __shared__ int rcnt[RB];
    __shared__ int rcur[RB];
    __shared__ int sscan[256];

    int b = blockIdx.x;
    int t = threadIdx.x;
    int nrec = cur[b]; if (nrec > CAP) nrec = CAP;
    const int2* src = arena  + (size_t)b * CAP;
    int2*       dst = arena2 + (size_t)b * CAP;

    for (int i = t; i < RB; i += 256) rcnt[i] = 0;
    __syncthreads();

    for (int i = t; i < nrec; i += 256)
        atomicAdd(&rcnt[src[i].x >> 17], 1);
    __syncthreads();

    int v = (t < RB) ? rcnt[t] : 0;
    sscan[t] = v;
    __syncthreads();
#pragma unroll
    for (int d = 1; d < 256; d <<= 1) {
        int u = (t >= d) ? sscan[t - d] : 0;
        __syncthreads();
        sscan[t] += u;
        __syncthreads();
    }
    if (t < RB) {
        int start = sscan[t] - v;
        rcur[t] = start;
        int grow = b * RB + t;
        if (grow < nrows)
            rowoff[grow] = make_int2(b * CAP + start, b * CAP + start + v);
    }
    __syncthreads();

    for (int i = t; i < nrec; i += 256) {
        int2 rec = src[i];
        int pos = atomicAdd(&rcur[rec.x >> 17], 1);
        dst[pos] = rec;
    }
}

// ---------------------------------------------------------------------------
// One wave per row, 4-deep unrolled bf16 gather, register acc, fused
// finalize: out[r] = wx[r] * acc (wx f32 in d_out, in-place).
// ---------------------------------------------------------------------------
__global__ __launch_bounds__(256) void agg_row_kernel(
    const int2* __restrict__ rowoff, const int2* __restrict__ arena2,
    const unsigned int* __restrict__ wxh32, float* __restrict__ outwx,
    int nrows)
{
    int wid  = (blockIdx.x * 256 + threadIdx.x) >> 6;
    int lane = threadIdx.x & 63;
    if (wid >= nrows) return;

    int2 se   = rowoff[wid];
    int start = __builtin_amdgcn_readfirstlane(se.x);
    int end   = __builtin_amdgcn_readfirstlane(se.y);

    float accx = 0.f, accy = 0.f;
    int e = start;
    for (; e + 3 < end; e += 4) {
        int2 r0 = arena2[e];
        int2 r1 = arena2[e + 1];
        int2 r2 = arena2[e + 2];
        int2 r3 = arena2[e + 3];
        unsigned int g0 = wxh32[(size_t)(r0.x & 0x1FFFF) * 64 + lane];
        unsigned int g1 = wxh32[(size_t)(r1.x & 0x1FFFF) * 64 + lane];
        unsigned int g2 = wxh32[(size_t)(r2.x & 0x1FFFF) * 64 + lane];
        unsigned int g3 = wxh32[(size_t)(r3.x & 0x1FFFF) * 64 + lane];
        float v0 = __int_as_float(r0.y), v1 = __int_as_float(r1.y);
        float v2 = __int_as_float(r2.y), v3 = __int_as_float(r3.y);
        accx = fmaf(v0, __uint_as_float(g0 << 16), accx);
        accy = fmaf(v0, __uint_as_float(g0 & 0xFFFF0000u), accy);
        accx = fmaf(v1, __uint_as_float(g1 << 16), accx);
        accy = fmaf(v1, __uint_as_float(g1 & 0xFFFF0000u), accy);
        accx = fmaf(v2, __uint_as_float(g2 << 16), accx);
        accy = fmaf(v2, __uint_as_float(g2 & 0xFFFF0000u), accy);
        accx = fmaf(v3, __uint_as_float(g3 << 16), accx);
        accy = fmaf(v3, __uint_as_float(g3 & 0xFFFF0000u), accy);
    }
    for (; e < end; ++e) {
        int2 r0 = arena2[e];
        unsigned int g0 = wxh32[(size_t)(r0.x & 0x1FFFF) * 64 + lane];
        float v0 = __int_as_float(r0.y);
        accx = fmaf(v0, __uint_as_float(g0 << 16), accx);
        accy = fmaf(v0, __uint_as_float(g0 & 0xFFFF0000u), accy);
    }

    float2 wr = *reinterpret_cast<const float2*>(outwx + (size_t)wid * F + lane * 2);
    float2 o;
    o.x = wr.x * accx;
    o.y = wr.y * accy;
    *reinterpret_cast<float2*>(outwx + (size_t)wid * F + lane * 2) = o;
}

// ---------------------------------------------------------------------------
// Last-resort fallback (round-1, proven): atomic scatter + finalize
// ---------------------------------------------------------------------------
__global__ __launch_bounds__(256) void edge_scatter_kernel(
    const int* __restrict__ rowi, const int* __restrict__ coli,
    const float* __restrict__ ev, const float* __restrict__ wx,
    float* __restrict__ temp, int E)
{
    int tid = blockIdx.x * 256 + threadIdx.x;
    int e   = tid >> 5;
    if (e >= E) return;
    int lane = tid & 31;
    int r = rowi[e];
    int c = coli[e];
    if (r == c) return;
    float v = ev[e];
    v = v * v;
    const float4 wv = *reinterpret_cast<const float4*>(wx + (size_t)c * F + lane * 4);
    float* tp = temp + (size_t)r * F + lane * 4;
    atomicAdd(tp + 0, v * wv.x);
    atomicAdd(tp + 1, v * wv.y);
    atomicAdd(tp + 2, v * wv.z);
    atomicAdd(tp + 3, v * wv.w);
}

__global__ __launch_bounds__(256) void finalize_kernel(
    float* __restrict__ out, const float* __restrict__ temp, int n4)
{
    int i = blockIdx.x * 256 + threadIdx.x;
    if (i >= n4) return;
    float4 o  = reinterpret_cast<float4*>(out)[i];
    float4 tv = reinterpret_cast<const float4*>(temp)[i];
    o.x *= tv.x; o.y *= tv.y; o.z *= tv.z; o.w *= tv.w;
    reinterpret_cast<float4*>(out)[i] = o;
}

__global__ void Interaction_GraphConvolution_55963423867450_kernel() {}

extern "C" void kernel_launch(void* const* d_in, const int* in_sizes, int n_in,
                              void* d_out, int out_size, void* d_ws, size_t ws_size,
                              hipStream_t stream)
{
    const float* X  = (const float*)d_in[0];
    const int*   ei = (const int*)d_in[1];   // [2, E] int32
    const float* ev = (const float*)d_in[2];
    const float* W  = (const float*)d_in[3];
    const float* b  = (const float*)d_in[4];
    float* out = (float*)d_out;

    int nrows = in_sizes[0] / F;
    int E     = in_sizes[2];
    const int* rowi = ei;
    const int* coli = ei + E;

    int gblocks = (int)((nrows + 127) / 128);

    int NB = (nrows + RB - 1) / RB;
    if (NB <= NB_MAX) {
        long avg = (long)E / NB;
        int CAP = (int)(((avg * 5) / 4 + 512 + 7) & ~7L);

        char* p = (char*)d_ws;
        __hip_bfloat16* wxh = (__hip_bfloat16*)p;
        p += (size_t)nrows * F * sizeof(__hip_bfloat16);
        int* cur = (int*)p;
        p += (size_t)((NB + 3) & ~3) * sizeof(int);
        p = (char*)(((uintptr_t)p + 63) & ~(uintptr_t)63);
        int2* rowoff = (int2*)p;
        p += (size_t)nrows * sizeof(int2);
        int2* arena = (int2*)p;
        p += (size_t)NB * CAP * sizeof(int2);
        int2* arena2 = (int2*)p;
        p += (size_t)NB * CAP * sizeof(int2);
        size_t need = (size_t)(p - (char*)d_ws);

        if (ws_size >= need) {
            hipMemsetAsync(cur, 0, (size_t)NB * sizeof(int), stream);
            gemm_mfma_kernel<<<gblocks, 256, 0, stream>>>(X, W, b, out, wxh, nrows);
            bin_edges_kernel<<<NBLK_BIN, 256, 0, stream>>>(rowi, coli, ev, cur,
                                                           arena, E, NB, CAP);
            sort_bucket_kernel<<<NB, 256, 0, stream>>>(cur, arena, arena2,
                                                       rowoff, nrows, CAP);
            int ablocks = (int)(((long)nrows * 64 + 255) / 256);
            agg_row_kernel<<<ablocks, 256, 0, stream>>>(rowoff, arena2,
                                                        (const unsigned int*)wxh,
                                                        out, nrows);
            return;
        }
    }

    // ---------- last resort: atomic scatter (round-1) ----------
    float* temp = (float*)d_ws;   // [nrows, 128]
    hipMemsetAsync(temp, 0, (size_t)nrows * F * sizeof(float), stream);
    __hip_bfloat16* wxh_dummy = (__hip_bfloat16*)((char*)d_ws + (size_t)nrows * F * sizeof(float));
    gemm_mfma_kernel<<<gblocks, 256, 0, stream>>>(X, W, b, out, wxh_dummy, nrows);
    long ethreads = (long)E * 32;
    int  eblocks32 = (int)((ethreads + 255) / 256);
    edge_scatter_kernel<<<eblocks32, 256, 0, stream>>>(rowi, coli, ev, out, temp, E);
    int n4 = nrows * F / 4;
    finalize_kernel<<<(n4 + 255) / 256, 256, 0, stream>>>(out, temp, n4);
}

// Round 8
// 224.616 us; speedup vs baseline: 10.7863x; 1.4805x over previous
//
#include <hip/hip_runtime.h>
#include <hip/hip_bf16.h>

#define F 128
#define RB 196            // rows per bucket
#define NB_MAX 511        // max buckets (nrows <= 100156)
#define BIN_CAP 16        // LDS records per bin (circular)
#define NBLK_BIN 512      // bin_edges grid (2 blocks/CU)
#define NXS 16            // cursor/arena sub-segments (atomic de-contention)

typedef __attribute__((ext_vector_type(8))) short bf16x8;
typedef __attribute__((ext_vector_type(4))) float f32x4;

static __device__ __forceinline__ short f2bf(float f) {
    __hip_bfloat16 h = __float2bfloat16(f);
    return __builtin_bit_cast(short, h);
}

// ---------------------------------------------------------------------------
// MFMA GEMM (proven round 7): wx = X @ W.T + b, 128x128 tile, K=128.
// ---------------------------------------------------------------------------
__global__ __launch_bounds__(256) void gemm_mfma_kernel(
    const float* __restrict__ X, const float* __restrict__ W,
    const float* __restrict__ bias, float* __restrict__ wxf,
    __hip_bfloat16* __restrict__ wxh, int nrows)
{
    __shared__ short xs[128][136];
    __shared__ short wt[128][136];
    __shared__ float bsh[128];

    int t = threadIdx.x;
    long row0 = (long)blockIdx.x * 128;

    {
        int r = t >> 1, h = t & 1;
        const float4* src = reinterpret_cast<const float4*>(W + r * F + h * 64);
#pragma unroll
        for (int i = 0; i < 16; ++i) {
            float4 v = src[i];
            short4 s;
            s.x = f2bf(v.x); s.y = f2bf(v.y); s.z = f2bf(v.z); s.w = f2bf(v.w);
            *reinterpret_cast<short4*>(&wt[r][h * 64 + i * 4]) = s;
        }
        if (t < 128) bsh[t] = bias[t];
    }
    {
        int r = t >> 1, h = t & 1;
        long gr = row0 + r; if (gr > nrows - 1) gr = nrows - 1;
        const float4* src = reinterpret_cast<const float4*>(X + gr * F + h * 64);
#pragma unroll
        for (int i = 0; i < 16; ++i) {
            float4 v = src[i];
            short4 s;
            s.x = f2bf(v.x); s.y = f2bf(v.y); s.z = f2bf(v.z); s.w = f2bf(v.w);
            *reinterpret_cast<short4*>(&xs[r][h * 64 + i * 4]) = s;
        }
    }
    __syncthreads();

    int wave = t >> 6, lane = t & 63;
    int l15 = lane & 15, lg = lane >> 4;
    int mrow = wave * 32;

    float bj[8];
#pragma unroll
    for (int nf = 0; nf < 8; ++nf) bj[nf] = bsh[nf * 16 + l15];

    f32x4 acc[2][8] = {};

#pragma unroll
    for (int ks = 0; ks < 4; ++ks) {
        bf16x8 a0 = *reinterpret_cast<const bf16x8*>(&xs[mrow + l15][ks * 32 + lg * 8]);
        bf16x8 a1 = *reinterpret_cast<const bf16x8*>(&xs[mrow + 16 + l15][ks * 32 + lg * 8]);
#pragma unroll
        for (int nf = 0; nf < 8; ++nf) {
            bf16x8 bfr = *reinterpret_cast<const bf16x8*>(&wt[nf * 16 + l15][ks * 32 + lg * 8]);
            acc[0][nf] = __builtin_amdgcn_mfma_f32_16x16x32_bf16(a0, bfr, acc[0][nf], 0, 0, 0);
            acc[1][nf] = __builtin_amdgcn_mfma_f32_16x16x32_bf16(a1, bfr, acc[1][nf], 0, 0, 0);
        }
    }

#pragma unroll
    for (int mf = 0; mf < 2; ++mf) {
#pragma unroll
        for (int i = 0; i < 4; ++i) {
            long grow = row0 + mrow + mf * 16 + lg * 4 + i;
            if (grow < nrows) {
#pragma unroll
                for (int nf = 0; nf < 8; ++nf) {
                    float v = acc[mf][nf][i] + bj[nf];
                    int col = nf * 16 + l15;
                    wxf[grow * F + col] = v;
                    wxh[grow * F + col] = __float2bfloat16(v);
                }
            }
        }
    }
}

// ---------------------------------------------------------------------------
// Counting-bin v2: LDS write-combining + 16-way split cursors/arenas
// (atomic de-contention) + prefetch pipeline. Record = (rl<<17 | c, v^2);
// diagonal edges carry v^2 = 0. Chunk flushes are 64B-aligned full lines.
// ---------------------------------------------------------------------------
__global__ __launch_bounds__(256) void bin_edges_kernel(
    const int* __restrict__ rowi, const int* __restrict__ coli,
    const float* __restrict__ ev, int* __restrict__ cur2,
    int2* __restrict__ arena1, int E, int NB, int CAPX)
{
    __shared__ int2 bins[NB_MAX][BIN_CAP];
    __shared__ int  cnt[NB_MAX];
    __shared__ int  flushed[NB_MAX];

    int t = threadIdx.x;
    int x = blockIdx.x & (NXS - 1);
    for (int i = t; i < NB; i += 256) { cnt[i] = 0; flushed[i] = 0; }
    __syncthreads();

    long per   = ((long)E + NBLK_BIN - 1) / NBLK_BIN;
    long start = (long)blockIdx.x * per;
    long endE  = start + per; if (endE > E) endE = E;

    // prefetch batch 0
    int r = 0, c = 0; float v = 0.f;
    {
        long i0 = start + t;
        if (i0 < endE) { r = rowi[i0]; c = coli[i0]; v = ev[i0]; }
    }

    for (long base = start; base < endE; base += 256) {
        // insert current batch (registers)
        if (base + t < endE) {
            float v2 = (r != c) ? v * v : 0.0f;
            int b  = r / RB;
            int rl = r - b * RB;
            int pos = atomicAdd(&cnt[b], 1);
            bins[b][pos & (BIN_CAP - 1)] = make_int2((rl << 17) | c, __float_as_int(v2));
        }
        // prefetch next batch (loads overlap flush phase)
        int rn = 0, cn = 0; float vn = 0.f;
        {
            long i2 = base + 256 + t;
            if (i2 < endE) { rn = rowi[i2]; cn = coli[i2]; vn = ev[i2]; }
        }
        __syncthreads();
        for (int bb = t; bb < NB; bb += 256) {
            while (cnt[bb] - flushed[bb] >= 8) {
                int gpos = atomicAdd(&cur2[x * NB + bb], 8);
                if (gpos + 8 <= CAPX) {
                    const int2* src = &bins[bb][flushed[bb] & (BIN_CAP - 1)];
                    int2* dst = &arena1[((size_t)x * NB + bb) * CAPX + gpos];
                    const int4* s4 = (const int4*)src;
                    int4* d4 = (int4*)dst;
                    d4[0] = s4[0]; d4[1] = s4[1]; d4[2] = s4[2]; d4[3] = s4[3];
                }
                flushed[bb] += 8;
            }
        }
        __syncthreads();
        r = rn; c = cn; v = vn;
    }
    // final flush: dense remainder
    for (int bb = t; bb < NB; bb += 256) {
        int rem = cnt[bb] - flushed[bb];
        if (rem > 0) {
            int gpos = atomicAdd(&cur2[x * NB + bb], rem);
            if (gpos + rem <= CAPX) {
                int2* dst = &arena1[((size_t)x * NB + bb) * CAPX + gpos];
                for (int k = 0; k < rem; ++k)
                    dst[k] = bins[bb][(flushed[bb] + k) & (BIN_CAP - 1)];
            }
        }
    }
}

// ---------------------------------------------------------------------------
// Bucket-local counting sort v2: gather the bucket's NXS arena segments,
// count per-row (LDS), scan, scatter per-row-ordered into arena2, emit
// rowoff = (start,end) absolute indices into arena2.
// ---------------------------------------------------------------------------
__global__ __launch_bounds__(256) void sort_bucket_kernel(
    const int* __restrict__ cur2, const int2* __restrict__ arena1,
    int2* __restrict__ arena2, int2* __restrict__ rowoff,
    int nrows, int NB, int CAPX, int CAP)
{
    __shared__ int rcnt[RB];
    __shared__ int rcur[RB];
    __shared__ int sscan[256];

    int b = blockIdx.x;
    int t = threadIdx.x;
    int2* dst = arena2 + (size_t)b * CAP;

    for (int i = t; i < RB; i += 256) rcnt[i] = 0;
    __syncthreads();

    for (int x = 0; x < NXS; ++x) {
        int n_x = cur2[x * NB + b]; if (n_x > CAPX) n_x = CAPX;
        const int2* seg = arena1 + ((size_t)x * NB + b) * CAPX;
        for (int i = t; i < n_x; i += 256)
            atomicAdd(&rcnt[seg[i].x >> 17], 1);
    }
    __syncthreads();

    int v = (t < RB) ? rcnt[t] : 0;
    sscan[t] = v;
    __syncthreads();
#pragma unroll
    for (int d = 1; d < 256; d <<= 1) {
        int u = (t >= d) ? sscan[t - d] : 0;
        __syncthreads();
        sscan[t] += u;
        __syncthreads();
    }
    if (t < RB) {
        int start = sscan[t] - v;
        rcur[t] = start;
        int grow = b * RB + t;
        if (grow < nrows)
            rowoff[grow] = make_int2(b * CAP + start, b * CAP + start + v);
    }
    __syncthreads();

    for (int x = 0; x < NXS; ++x) {
        int n_x = cur2[x * NB + b]; if (n_x > CAPX) n_x = CAPX;
        const int2* seg = arena1 + ((size_t)x * NB + b) * CAPX;
        for (int i = t; i < n_x; i += 256) {
            int2 rec = seg[i];
            int pos = atomicAdd(&rcur[rec.x >> 17], 1);
            if (pos < CAP) dst[pos] = rec;
        }
    }
}

// ---------------------------------------------------------------------------
// One wave per row, 4-deep unrolled bf16 gather, register acc, fused
// finalize: out[r] = wx[r] * acc (wx f32 in d_out, in-place). (proven)
// ---------------------------------------------------------------------------
__global__ __launch_bounds__(256) void agg_row_kernel(
    const int2* __restrict__ rowoff, const int2* __restrict__ arena2,
    const unsigned int* __restrict__ wxh32, float* __restrict__ outwx,
    int nrows)
{
    int wid  = (blockIdx.x * 256 + threadIdx.x) >> 6;
    int lane = threadIdx.x & 63;
    if (wid >= nrows) return;

    int2 se   = rowoff[wid];
    int start = __builtin_amdgcn_readfirstlane(se.x);
    int end   = __builtin_amdgcn_readfirstlane(se.y);

    float accx = 0.f, accy = 0.f;
    int e = start;
    for (; e + 3 < end; e += 4) {
        int2 r0 = arena2[e];
        int2 r1 = arena2[e + 1];
        int2 r2 = arena2[e + 2];
        int2 r3 = arena2[e + 3];
        unsigned int g0 = wxh32[(size_t)(r0.x & 0x1FFFF) * 64 + lane];
        unsigned int g1 = wxh32[(size_t)(r1.x & 0x1FFFF) * 64 + lane];
        unsigned int g2 = wxh32[(size_t)(r2.x & 0x1FFFF) * 64 + lane];
        unsigned int g3 = wxh32[(size_t)(r3.x & 0x1FFFF) * 64 + lane];
        float v0 = __int_as_float(r0.y), v1 = __int_as_float(r1.y);
        float v2 = __int_as_float(r2.y), v3 = __int_as_float(r3.y);
        accx = fmaf(v0, __uint_as_float(g0 << 16), accx);
        accy = fmaf(v0, __uint_as_float(g0 & 0xFFFF0000u), accy);
        accx = fmaf(v1, __uint_as_float(g1 << 16), accx);
        accy = fmaf(v1, __uint_as_float(g1 & 0xFFFF0000u), accy);
        accx = fmaf(v2, __uint_as_float(g2 << 16), accx);
        accy = fmaf(v2, __uint_as_float(g2 & 0xFFFF0000u), accy);
        accx = fmaf(v3, __uint_as_float(g3 << 16), accx);
        accy = fmaf(v3, __uint_as_float(g3 & 0xFFFF0000u), accy);
    }
    for (; e < end; ++e) {
        int2 r0 = arena2[e];
        unsigned int g0 = wxh32[(size_t)(r0.x & 0x1FFFF) * 64 + lane];
        float v0 = __int_as_float(r0.y);
        accx = fmaf(v0, __uint_as_float(g0 << 16), accx);
        accy = fmaf(v0, __uint_as_float(g0 & 0xFFFF0000u), accy);
    }

    float2 wr = *reinterpret_cast<const float2*>(outwx + (size_t)wid * F + lane * 2);
    float2 o;
    o.x = wr.x * accx;
    o.y = wr.y * accy;
    *reinterpret_cast<float2*>(outwx + (size_t)wid * F + lane * 2) = o;
}

// ---------------------------------------------------------------------------
// Last-resort fallback (round-1, proven): atomic scatter + finalize
// ---------------------------------------------------------------------------
__global__ __launch_bounds__(256) void edge_scatter_kernel(
    const int* __restrict__ rowi, const int* __restrict__ coli,
    const float* __restrict__ ev, const float* __restrict__ wx,
    float* __restrict__ temp, int E)
{
    int tid = blockIdx.x * 256 + threadIdx.x;
    int e   = tid >> 5;
    if (e >= E) return;
    int lane = tid & 31;
    int r = rowi[e];
    int c = coli[e];
    if (r == c) return;
    float v = ev[e];
    v = v * v;
    const float4 wv = *reinterpret_cast<const float4*>(wx + (size_t)c * F + lane * 4);
    float* tp = temp + (size_t)r * F + lane * 4;
    atomicAdd(tp + 0, v * wv.x);
    atomicAdd(tp + 1, v * wv.y);
    atomicAdd(tp + 2, v * wv.z);
    atomicAdd(tp + 3, v * wv.w);
}

__global__ __launch_bounds__(256) void finalize_kernel(
    float* __restrict__ out, const float* __restrict__ temp, int n4)
{
    int i = blockIdx.x * 256 + threadIdx.x;
    if (i >= n4) return;
    float4 o  = reinterpret_cast<float4*>(out)[i];
    float4 tv = reinterpret_cast<const float4*>(temp)[i];
    o.x *= tv.x; o.y *= tv.y; o.z *= tv.z; o.w *= tv.w;
    reinterpret_cast<float4*>(out)[i] = o;
}

__global__ void Interaction_GraphConvolution_55963423867450_kernel() {}

extern "C" void kernel_launch(void* const* d_in, const int* in_sizes, int n_in,
                              void* d_out, int out_size, void* d_ws, size_t ws_size,
                              hipStream_t stream)
{
    const float* X  = (const float*)d_in[0];
    const int*   ei = (const int*)d_in[1];   // [2, E] int32
    const float* ev = (const float*)d_in[2];
    const float* W  = (const float*)d_in[3];
    const float* b  = (const float*)d_in[4];
    float* out = (float*)d_out;

    int nrows = in_sizes[0] / F;
    int E     = in_sizes[2];
    const int* rowi = ei;
    const int* coli = ei + E;

    int gblocks = (int)((nrows + 127) / 128);

    int NB = (nrows + RB - 1) / RB;
    if (NB <= NB_MAX) {
        long avg = (long)E / NB;                       // records per bucket
        int CAP  = (int)(((avg * 9) / 8 + 192 + 7) & ~7L);   // arena2 per-bucket (+~12 sigma)
        int CAPX = (int)(((avg / NXS) * 5 / 4 + 64 + 7) & ~7L); // per (x,bucket) segment

        char* p = (char*)d_ws;
        __hip_bfloat16* wxh = (__hip_bfloat16*)p;
        p += (size_t)nrows * F * sizeof(__hip_bfloat16);
        int* cur2 = (int*)p;
        p += (size_t)NXS * NB * sizeof(int);
        p = (char*)(((uintptr_t)p + 63) & ~(uintptr_t)63);
        int2* rowoff = (int2*)p;
        p += (size_t)nrows * sizeof(int2);
        int2* arena1 = (int2*)p;
        p += (size_t)NXS * NB * CAPX * sizeof(int2);
        int2* arena2 = (int2*)p;
        p += (size_t)NB * CAP * sizeof(int2);
        size_t need = (size_t)(p - (char*)d_ws);

        if (ws_size >= need) {
            hipMemsetAsync(cur2, 0, (size_t)NXS * NB * sizeof(int), stream);
            gemm_mfma_kernel<<<gblocks, 256, 0, stream>>>(X, W, b, out, wxh, nrows);
            bin_edges_kernel<<<NBLK_BIN, 256, 0, stream>>>(rowi, coli, ev, cur2,
                                                           arena1, E, NB, CAPX);
            sort_bucket_kernel<<<NB, 256, 0, stream>>>(cur2, arena1, arena2,
                                                       rowoff, nrows, NB, CAPX, CAP);
            int ablocks = (int)(((long)nrows * 64 + 255) / 256);
            agg_row_kernel<<<ablocks, 256, 0, stream>>>(rowoff, arena2,
                                                        (const unsigned int*)wxh,
                                                        out, nrows);
            return;
        }
    }

    // ---------- last resort: atomic scatter (round-1) ----------
    float* temp = (float*)d_ws;   // [nrows, 128]
    hipMemsetAsync(temp, 0, (size_t)nrows * F * sizeof(float), stream);
    __hip_bfloat16* wxh_dummy = (__hip_bfloat16*)((char*)d_ws + (size_t)nrows * F * sizeof(float));
    gemm_mfma_kernel<<<(int)((nrows + 127) / 128), 256, 0, stream>>>(X, W, b, out, wxh_dummy, nrows);
    long ethreads = (long)E * 32;
    int  eblocks32 = (int)((ethreads + 255) / 256);
    edge_scatter_kernel<<<eblocks32, 256, 0, stream>>>(rowi, coli, ev, out, temp, E);
    int n4 = nrows * F / 4;
    finalize_kernel<<<(n4 + 255) / 256, 256, 0, stream>>>(out, temp, n4);
}

// Round 9
// 218.854 us; speedup vs baseline: 11.0703x; 1.0263x over previous
//
#include <hip/hip_runtime.h>
#include <hip/hip_bf16.h>

#define F 128
#define RB 196            // rows per bucket
#define NB_MAX 511        // max buckets (nrows <= 100156)
#define BIN_CAP 16        // LDS records per bin (circular)
#define NBLK_BIN 512      // bin_edges grid (2 blocks/CU)
#define NXS 16            // cursor/arena sub-segments (atomic de-contention)
#define NCG 16            // column groups (c >> 13) for gather locality
#define KEYS (RB * NCG)   // 3136 sort keys per bucket

typedef __attribute__((ext_vector_type(8))) short bf16x8;
typedef __attribute__((ext_vector_type(4))) float f32x4;

static __device__ __forceinline__ unsigned short f2bfbits(float f) {
    __hip_bfloat16 h = __float2bfloat16(f);
    return __builtin_bit_cast(unsigned short, h);
}
static __device__ __forceinline__ short f2bf(float f) {
    __hip_bfloat16 h = __float2bfloat16(f);
    return __builtin_bit_cast(short, h);
}

// ---------------------------------------------------------------------------
// MFMA GEMM (proven): wx = X @ W.T + b, 128x128 tile, K=128.
// ---------------------------------------------------------------------------
__global__ __launch_bounds__(256) void gemm_mfma_kernel(
    const float* __restrict__ X, const float* __restrict__ W,
    const float* __restrict__ bias, float* __restrict__ wxf,
    __hip_bfloat16* __restrict__ wxh, int nrows)
{
    __shared__ short xs[128][136];
    __shared__ short wt[128][136];
    __shared__ float bsh[128];

    int t = threadIdx.x;
    long row0 = (long)blockIdx.x * 128;

    {
        int r = t >> 1, h = t & 1;
        const float4* src = reinterpret_cast<const float4*>(W + r * F + h * 64);
#pragma unroll
        for (int i = 0; i < 16; ++i) {
            float4 v = src[i];
            short4 s;
            s.x = f2bf(v.x); s.y = f2bf(v.y); s.z = f2bf(v.z); s.w = f2bf(v.w);
            *reinterpret_cast<short4*>(&wt[r][h * 64 + i * 4]) = s;
        }
        if (t < 128) bsh[t] = bias[t];
    }
    {
        int r = t >> 1, h = t & 1;
        long gr = row0 + r; if (gr > nrows - 1) gr = nrows - 1;
        const float4* src = reinterpret_cast<const float4*>(X + gr * F + h * 64);
#pragma unroll
        for (int i = 0; i < 16; ++i) {
            float4 v = src[i];
            short4 s;
            s.x = f2bf(v.x); s.y = f2bf(v.y); s.z = f2bf(v.z); s.w = f2bf(v.w);
            *reinterpret_cast<short4*>(&xs[r][h * 64 + i * 4]) = s;
        }
    }
    __syncthreads();

    int wave = t >> 6, lane = t & 63;
    int l15 = lane & 15, lg = lane >> 4;
    int mrow = wave * 32;

    float bj[8];
#pragma unroll
    for (int nf = 0; nf < 8; ++nf) bj[nf] = bsh[nf * 16 + l15];

    f32x4 acc[2][8] = {};

#pragma unroll
    for (int ks = 0; ks < 4; ++ks) {
        bf16x8 a0 = *reinterpret_cast<const bf16x8*>(&xs[mrow + l15][ks * 32 + lg * 8]);
        bf16x8 a1 = *reinterpret_cast<const bf16x8*>(&xs[mrow + 16 + l15][ks * 32 + lg * 8]);
#pragma unroll
        for (int nf = 0; nf < 8; ++nf) {
            bf16x8 bfr = *reinterpret_cast<const bf16x8*>(&wt[nf * 16 + l15][ks * 32 + lg * 8]);
            acc[0][nf] = __builtin_amdgcn_mfma_f32_16x16x32_bf16(a0, bfr, acc[0][nf], 0, 0, 0);
            acc[1][nf] = __builtin_amdgcn_mfma_f32_16x16x32_bf16(a1, bfr, acc[1][nf], 0, 0, 0);
        }
    }

#pragma unroll
    for (int mf = 0; mf < 2; ++mf) {
#pragma unroll
        for (int i = 0; i < 4; ++i) {
            long grow = row0 + mrow + mf * 16 + lg * 4 + i;
            if (grow < nrows) {
#pragma unroll
                for (int nf = 0; nf < 8; ++nf) {
                    float v = acc[mf][nf][i] + bj[nf];
                    int col = nf * 16 + l15;
                    wxf[grow * F + col] = v;
                    wxh[grow * F + col] = __float2bfloat16(v);
                }
            }
        }
    }
}

// ---------------------------------------------------------------------------
// Counting-bin (proven): LDS write-combining + 16-way split cursors/arenas
// + prefetch. arena1 record = (rl<<17 | c, v^2 f32); diagonal v^2 = 0.
// ---------------------------------------------------------------------------
__global__ __launch_bounds__(256) void bin_edges_kernel(
    const int* __restrict__ rowi, const int* __restrict__ coli,
    const float* __restrict__ ev, int* __restrict__ cur2,
    int2* __restrict__ arena1, int E, int NB, int CAPX)
{
    __shared__ int2 bins[NB_MAX][BIN_CAP];
    __shared__ int  cnt[NB_MAX];
    __shared__ int  flushed[NB_MAX];

    int t = threadIdx.x;
    int x = blockIdx.x & (NXS - 1);
    for (int i = t; i < NB; i += 256) { cnt[i] = 0; flushed[i] = 0; }
    __syncthreads();

    long per   = ((long)E + NBLK_BIN - 1) / NBLK_BIN;
    long start = (long)blockIdx.x * per;
    long endE  = start + per; if (endE > E) endE = E;

    int r = 0, c = 0; float v = 0.f;
    {
        long i0 = start + t;
        if (i0 < endE) { r = rowi[i0]; c = coli[i0]; v = ev[i0]; }
    }

    for (long base = start; base < endE; base += 256) {
        if (base + t < endE) {
            float v2 = (r != c) ? v * v : 0.0f;
            int b  = r / RB;
            int rl = r - b * RB;
            int pos = atomicAdd(&cnt[b], 1);
            bins[b][pos & (BIN_CAP - 1)] = make_int2((rl << 17) | c, __float_as_int(v2));
        }
        int rn = 0, cn = 0; float vn = 0.f;
        {
            long i2 = base + 256 + t;
            if (i2 < endE) { rn = rowi[i2]; cn = coli[i2]; vn = ev[i2]; }
        }
        __syncthreads();
        for (int bb = t; bb < NB; bb += 256) {
            while (cnt[bb] - flushed[bb] >= 8) {
                int gpos = atomicAdd(&cur2[x * NB + bb], 8);
                if (gpos + 8 <= CAPX) {
                    const int2* src = &bins[bb][flushed[bb] & (BIN_CAP - 1)];
                    int2* dst = &arena1[((size_t)x * NB + bb) * CAPX + gpos];
                    const int4* s4 = (const int4*)src;
                    int4* d4 = (int4*)dst;
                    d4[0] = s4[0]; d4[1] = s4[1]; d4[2] = s4[2]; d4[3] = s4[3];
                }
                flushed[bb] += 8;
            }
        }
        __syncthreads();
        r = rn; c = cn; v = vn;
    }
    for (int bb = t; bb < NB; bb += 256) {
        int rem = cnt[bb] - flushed[bb];
        if (rem > 0) {
            int gpos = atomicAdd(&cur2[x * NB + bb], rem);
            if (gpos + rem <= CAPX) {
                int2* dst = &arena1[((size_t)x * NB + bb) * CAPX + gpos];
                for (int k = 0; k < rem; ++k)
                    dst[k] = bins[bb][(flushed[bb] + k) & (BIN_CAP - 1)];
            }
        }
    }
}

// ---------------------------------------------------------------------------
// Bucket-local counting sort v3: key = rl*NCG + (c>>13) so each row's
// records come out ordered by 2MB column window (gather locality in agg).
// arena2 record packed to 4B: (bf16bits(v^2) << 17) | c  (sign bit of v^2
// is 0 since v^2 >= 0; c < 2^17). rowoff = (start,end) into arena2.
// ---------------------------------------------------------------------------
__global__ __launch_bounds__(256) void sort_bucket_kernel(
    const int* __restrict__ cur2, const int2* __restrict__ arena1,
    unsigned int* __restrict__ arena2, int2* __restrict__ rowoff,
    int nrows, int NB, int CAPX, int CAP)
{
    __shared__ int koff[KEYS];    // counts -> offsets -> cursors
    __shared__ int sscan[256];

    int b = blockIdx.x;
    int t = threadIdx.x;
    unsigned int* dst = arena2 + (size_t)b * CAP;

    for (int i = t; i < KEYS; i += 256) koff[i] = 0;
    __syncthreads();

    // pass 1: count keys
    for (int x = 0; x < NXS; ++x) {
        int n_x = cur2[x * NB + b]; if (n_x > CAPX) n_x = CAPX;
        const int2* seg = arena1 + ((size_t)x * NB + b) * CAPX;
        for (int i = t; i < n_x; i += 256) {
            int rx = seg[i].x;
            int key = (rx >> 17) * NCG + ((rx & 0x1FFFF) >> 13);
            atomicAdd(&koff[key], 1);
        }
    }
    __syncthreads();

    // hierarchical exclusive scan over KEYS (per-thread chunk + block scan)
    const int PER = (KEYS + 255) / 256;   // 13
    int lo = t * PER, hi = lo + PER; if (hi > KEYS) hi = KEYS; if (lo > KEYS) lo = KEYS;
    int s = 0;
    for (int i = lo; i < hi; ++i) s += koff[i];
    sscan[t] = s;
    __syncthreads();
#pragma unroll
    for (int d = 1; d < 256; d <<= 1) {
        int u = (t >= d) ? sscan[t - d] : 0;
        __syncthreads();
        sscan[t] += u;
        __syncthreads();
    }
    int total = sscan[255];
    int run = (t == 0) ? 0 : sscan[t - 1];
    for (int i = lo; i < hi; ++i) {
        int c0 = koff[i];
        koff[i] = run;
        run += c0;
    }
    __syncthreads();

    // rowoff (must happen before scatter destroys koff)
    if (t < RB) {
        int grow = b * RB + t;
        if (grow < nrows) {
            int start = koff[t * NCG];
            int end   = (t == RB - 1) ? total : koff[(t + 1) * NCG];
            rowoff[grow] = make_int2(b * CAP + start, b * CAP + end);
        }
    }
    __syncthreads();

    // pass 2: scatter, packing to 4B
    for (int x = 0; x < NXS; ++x) {
        int n_x = cur2[x * NB + b]; if (n_x > CAPX) n_x = CAPX;
        const int2* seg = arena1 + ((size_t)x * NB + b) * CAPX;
        for (int i = t; i < n_x; i += 256) {
            int2 rec = seg[i];
            int c = rec.x & 0x1FFFF;
            int key = (rec.x >> 17) * NCG + (c >> 13);
            int pos = atomicAdd(&koff[key], 1);
            unsigned int pk = ((unsigned int)f2bfbits(__int_as_float(rec.y)) << 17)
                              | (unsigned int)c;
            if (pos < CAP) dst[pos] = pk;
        }
    }
}

// ---------------------------------------------------------------------------
// One wave per row, 4-deep unrolled bf16 gather (records column-ordered),
// register acc, fused finalize: out[r] = wx[r] * acc (in-place on d_out).
// Decode: c = p & 0x1FFFF; v2 = bits (p>>17)<<16 (bf16, sign 0).
// ---------------------------------------------------------------------------
__global__ __launch_bounds__(256) void agg_row_kernel(
    const int2* __restrict__ rowoff, const unsigned int* __restrict__ arena2,
    const unsigned int* __restrict__ wxh32, float* __restrict__ outwx,
    int nrows)
{
    int wid  = (blockIdx.x * 256 + threadIdx.x) >> 6;
    int lane = threadIdx.x & 63;
    if (wid >= nrows) return;

    int2 se   = rowoff[wid];
    int start = __builtin_amdgcn_readfirstlane(se.x);
    int end   = __builtin_amdgcn_readfirstlane(se.y);

    float accx = 0.f, accy = 0.f;
    int e = start;
    for (; e + 3 < end; e += 4) {
        unsigned int p0 = arena2[e];
        unsigned int p1 = arena2[e + 1];
        unsigned int p2 = arena2[e + 2];
        unsigned int p3 = arena2[e + 3];
        unsigned int g0 = wxh32[(size_t)(p0 & 0x1FFFF) * 64 + lane];
        unsigned int g1 = wxh32[(size_t)(p1 & 0x1FFFF) * 64 + lane];
        unsigned int g2 = wxh32[(size_t)(p2 & 0x1FFFF) * 64 + lane];
        unsigned int g3 = wxh32[(size_t)(p3 & 0x1FFFF) * 64 + lane];
        float v0 = __uint_as_float((p0 >> 17) << 16);
        float v1 = __uint_as_float((p1 >> 17) << 16);
        float v2 = __uint_as_float((p2 >> 17) << 16);
        float v3 = __uint_as_float((p3 >> 17) << 16);
        accx = fmaf(v0, __uint_as_float(g0 << 16), accx);
        accy = fmaf(v0, __uint_as_float(g0 & 0xFFFF0000u), accy);
        accx = fmaf(v1, __uint_as_float(g1 << 16), accx);
        accy = fmaf(v1, __uint_as_float(g1 & 0xFFFF0000u), accy);
        accx = fmaf(v2, __uint_as_float(g2 << 16), accx);
        accy = fmaf(v2, __uint_as_float(g2 & 0xFFFF0000u), accy);
        accx = fmaf(v3, __uint_as_float(g3 << 16), accx);
        accy = fmaf(v3, __uint_as_float(g3 & 0xFFFF0000u), accy);
    }
    for (; e < end; ++e) {
        unsigned int p0 = arena2[e];
        unsigned int g0 = wxh32[(size_t)(p0 & 0x1FFFF) * 64 + lane];
        float v0 = __uint_as_float((p0 >> 17) << 16);
        accx = fmaf(v0, __uint_as_float(g0 << 16), accx);
        accy = fmaf(v0, __uint_as_float(g0 & 0xFFFF0000u), accy);
    }

    float2 wr = *reinterpret_cast<const float2*>(outwx + (size_t)wid * F + lane * 2);
    float2 o;
    o.x = wr.x * accx;
    o.y = wr.y * accy;
    *reinterpret_cast<float2*>(outwx + (size_t)wid * F + lane * 2) = o;
}

// ---------------------------------------------------------------------------
// Last-resort fallback (round-1, proven): atomic scatter + finalize
// ---------------------------------------------------------------------------
__global__ __launch_bounds__(256) void edge_scatter_kernel(
    const int* __restrict__ rowi, const int* __restrict__ coli,
    const float* __restrict__ ev, const float* __restrict__ wx,
    float* __restrict__ temp, int E)
{
    int tid = blockIdx.x * 256 + threadIdx.x;
    int e   = tid >> 5;
    if (e >= E) return;
    int lane = tid & 31;
    int r = rowi[e];
    int c = coli[e];
    if (r == c) return;
    float v = ev[e];
    v = v * v;
    const float4 wv = *reinterpret_cast<const float4*>(wx + (size_t)c * F + lane * 4);
    float* tp = temp + (size_t)r * F + lane * 4;
    atomicAdd(tp + 0, v * wv.x);
    atomicAdd(tp + 1, v * wv.y);
    atomicAdd(tp + 2, v * wv.z);
    atomicAdd(tp + 3, v * wv.w);
}

__global__ __launch_bounds__(256) void finalize_kernel(
    float* __restrict__ out, const float* __restrict__ temp, int n4)
{
    int i = blockIdx.x * 256 + threadIdx.x;
    if (i >= n4) return;
    float4 o  = reinterpret_cast<float4*>(out)[i];
    float4 tv = reinterpret_cast<const float4*>(temp)[i];
    o.x *= tv.x; o.y *= tv.y; o.z *= tv.z; o.w *= tv.w;
    reinterpret_cast<float4*>(out)[i] = o;
}

__global__ void Interaction_GraphConvolution_55963423867450_kernel() {}

extern "C" void kernel_launch(void* const* d_in, const int* in_sizes, int n_in,
                              void* d_out, int out_size, void* d_ws, size_t ws_size,
                              hipStream_t stream)
{
    const float* X  = (const float*)d_in[0];
    const int*   ei = (const int*)d_in[1];   // [2, E] int32
    const float* ev = (const float*)d_in[2];
    const float* W  = (const float*)d_in[3];
    const float* b  = (const float*)d_in[4];
    float* out = (float*)d_out;

    int nrows = in_sizes[0] / F;
    int E     = in_sizes[2];
    const int* rowi = ei;
    const int* coli = ei + E;

    int gblocks = (int)((nrows + 127) / 128);

    int NB = (nrows + RB - 1) / RB;
    if (NB <= NB_MAX && nrows < (1 << 17)) {
        long avg = (long)E / NB;                                 // records per bucket
        int CAP  = (int)(((avg * 9) / 8 + 192 + 7) & ~7L);       // arena2 per-bucket
        int CAPX = (int)(((avg / NXS) * 5 / 4 + 64 + 7) & ~7L);  // per (x,bucket) segment

        char* p = (char*)d_ws;
        __hip_bfloat16* wxh = (__hip_bfloat16*)p;
        p += (size_t)nrows * F * sizeof(__hip_bfloat16);
        int* cur2 = (int*)p;
        p += (size_t)NXS * NB * sizeof(int);
        p = (char*)(((uintptr_t)p + 63) & ~(uintptr_t)63);
        int2* rowoff = (int2*)p;
        p += (size_t)nrows * sizeof(int2);
        int2* arena1 = (int2*)p;
        p += (size_t)NXS * NB * CAPX * sizeof(int2);
        unsigned int* arena2 = (unsigned int*)p;
        p += (size_t)NB * CAP * sizeof(unsigned int);
        size_t need = (size_t)(p - (char*)d_ws);

        if (ws_size >= need) {
            hipMemsetAsync(cur2, 0, (size_t)NXS * NB * sizeof(int), stream);
            gemm_mfma_kernel<<<gblocks, 256, 0, stream>>>(X, W, b, out, wxh, nrows);
            bin_edges_kernel<<<NBLK_BIN, 256, 0, stream>>>(rowi, coli, ev, cur2,
                                                           arena1, E, NB, CAPX);
            sort_bucket_kernel<<<NB, 256, 0, stream>>>(cur2, arena1, arena2,
                                                       rowoff, nrows, NB, CAPX, CAP);
            int ablocks = (int)(((long)nrows * 64 + 255) / 256);
            agg_row_kernel<<<ablocks, 256, 0, stream>>>(rowoff, arena2,
                                                        (const unsigned int*)wxh,
                                                        out, nrows);
            return;
        }
    }

    // ---------- last resort: atomic scatter (round-1) ----------
    float* temp = (float*)d_ws;   // [nrows, 128]
    hipMemsetAsync(temp, 0, (size_t)nrows * F * sizeof(float), stream);
    __hip_bfloat16* wxh_dummy = (__hip_bfloat16*)((char*)d_ws + (size_t)nrows * F * sizeof(float));
    gemm_mfma_kernel<<<(int)((nrows + 127) / 128), 256, 0, stream>>>(X, W, b, out, wxh_dummy, nrows);
    long ethreads = (long)E * 32;
    int  eblocks32 = (int)((ethreads + 255) / 256);
    edge_scatter_kernel<<<eblocks32, 256, 0, stream>>>(rowi, coli, ev, out, temp, E);
    int n4 = nrows * F / 4;
    finalize_kernel<<<(n4 + 255) / 256, 256, 0, stream>>>(out, temp, n4);
}

// Round 10
// 215.978 us; speedup vs baseline: 11.2177x; 1.0133x over previous
//
#include <hip/hip_runtime.h>
#include <hip/hip_bf16.h>

#define F 128
#define RB 196            // rows per bucket
#define NB_MAX 511        // max buckets (nrows <= 100156)
#define BIN_CAP 16        // LDS records per bin (circular)
#define NBLK_BIN 512      // bin_edges grid (2 blocks/CU)
#define NXS 16            // cursor/arena sub-segments (atomic de-contention)
#define NCG 16            // column groups (c >> 13) for gather locality
#define KEYS (RB * NCG)   // 3136 sort keys per bucket

typedef __attribute__((ext_vector_type(8))) short bf16x8;
typedef __attribute__((ext_vector_type(4))) float f32x4;

static __device__ __forceinline__ unsigned short f2bfbits(float f) {
    __hip_bfloat16 h = __float2bfloat16(f);
    return __builtin_bit_cast(unsigned short, h);
}
static __device__ __forceinline__ short f2bf(float f) {
    __hip_bfloat16 h = __float2bfloat16(f);
    return __builtin_bit_cast(short, h);
}

// ---------------------------------------------------------------------------
// MFMA GEMM (proven): wx = X @ W.T + b, 128x128 tile, K=128.
// Main path: writes ONLY bf16 wxh (25.6 MB). Fallback: also f32 wxf.
// ---------------------------------------------------------------------------
__global__ __launch_bounds__(256) void gemm_mfma_kernel(
    const float* __restrict__ X, const float* __restrict__ W,
    const float* __restrict__ bias, float* __restrict__ wxf,
    __hip_bfloat16* __restrict__ wxh, int nrows, int writeF)
{
    __shared__ short xs[128][136];
    __shared__ short wt[128][136];
    __shared__ float bsh[128];

    int t = threadIdx.x;
    long row0 = (long)blockIdx.x * 128;

    {
        int r = t >> 1, h = t & 1;
        const float4* src = reinterpret_cast<const float4*>(W + r * F + h * 64);
#pragma unroll
        for (int i = 0; i < 16; ++i) {
            float4 v = src[i];
            short4 s;
            s.x = f2bf(v.x); s.y = f2bf(v.y); s.z = f2bf(v.z); s.w = f2bf(v.w);
            *reinterpret_cast<short4*>(&wt[r][h * 64 + i * 4]) = s;
        }
        if (t < 128) bsh[t] = bias[t];
    }
    {
        int r = t >> 1, h = t & 1;
        long gr = row0 + r; if (gr > nrows - 1) gr = nrows - 1;
        const float4* src = reinterpret_cast<const float4*>(X + gr * F + h * 64);
#pragma unroll
        for (int i = 0; i < 16; ++i) {
            float4 v = src[i];
            short4 s;
            s.x = f2bf(v.x); s.y = f2bf(v.y); s.z = f2bf(v.z); s.w = f2bf(v.w);
            *reinterpret_cast<short4*>(&xs[r][h * 64 + i * 4]) = s;
        }
    }
    __syncthreads();

    int wave = t >> 6, lane = t & 63;
    int l15 = lane & 15, lg = lane >> 4;
    int mrow = wave * 32;

    float bj[8];
#pragma unroll
    for (int nf = 0; nf < 8; ++nf) bj[nf] = bsh[nf * 16 + l15];

    f32x4 acc[2][8] = {};

#pragma unroll
    for (int ks = 0; ks < 4; ++ks) {
        bf16x8 a0 = *reinterpret_cast<const bf16x8*>(&xs[mrow + l15][ks * 32 + lg * 8]);
        bf16x8 a1 = *reinterpret_cast<const bf16x8*>(&xs[mrow + 16 + l15][ks * 32 + lg * 8]);
#pragma unroll
        for (int nf = 0; nf < 8; ++nf) {
            bf16x8 bfr = *reinterpret_cast<const bf16x8*>(&wt[nf * 16 + l15][ks * 32 + lg * 8]);
            acc[0][nf] = __builtin_amdgcn_mfma_f32_16x16x32_bf16(a0, bfr, acc[0][nf], 0, 0, 0);
            acc[1][nf] = __builtin_amdgcn_mfma_f32_16x16x32_bf16(a1, bfr, acc[1][nf], 0, 0, 0);
        }
    }

#pragma unroll
    for (int mf = 0; mf < 2; ++mf) {
#pragma unroll
        for (int i = 0; i < 4; ++i) {
            long grow = row0 + mrow + mf * 16 + lg * 4 + i;
            if (grow < nrows) {
#pragma unroll
                for (int nf = 0; nf < 8; ++nf) {
                    float v = acc[mf][nf][i] + bj[nf];
                    int col = nf * 16 + l15;
                    wxh[grow * F + col] = __float2bfloat16(v);
                    if (writeF) wxf[grow * F + col] = v;
                }
            }
        }
    }
}

// ---------------------------------------------------------------------------
// Counting-bin (proven): LDS write-combining + 16-way split cursors/arenas
// + prefetch. arena1 record = (rl<<17 | c, v^2 f32); diagonal v^2 = 0.
// ---------------------------------------------------------------------------
__global__ __launch_bounds__(256) void bin_edges_kernel(
    const int* __restrict__ rowi, const int* __restrict__ coli,
    const float* __restrict__ ev, int* __restrict__ cur2,
    int2* __restrict__ arena1, int E, int NB, int CAPX)
{
    __shared__ int2 bins[NB_MAX][BIN_CAP];
    __shared__ int  cnt[NB_MAX];
    __shared__ int  flushed[NB_MAX];

    int t = threadIdx.x;
    int x = blockIdx.x & (NXS - 1);
    for (int i = t; i < NB; i += 256) { cnt[i] = 0; flushed[i] = 0; }
    __syncthreads();

    long per   = ((long)E + NBLK_BIN - 1) / NBLK_BIN;
    long start = (long)blockIdx.x * per;
    long endE  = start + per; if (endE > E) endE = E;

    int r = 0, c = 0; float v = 0.f;
    {
        long i0 = start + t;
        if (i0 < endE) { r = rowi[i0]; c = coli[i0]; v = ev[i0]; }
    }

    for (long base = start; base < endE; base += 256) {
        if (base + t < endE) {
            float v2 = (r != c) ? v * v : 0.0f;
            int b  = r / RB;
            int rl = r - b * RB;
            int pos = atomicAdd(&cnt[b], 1);
            bins[b][pos & (BIN_CAP - 1)] = make_int2((rl << 17) | c, __float_as_int(v2));
        }
        int rn = 0, cn = 0; float vn = 0.f;
        {
            long i2 = base + 256 + t;
            if (i2 < endE) { rn = rowi[i2]; cn = coli[i2]; vn = ev[i2]; }
        }
        __syncthreads();
        for (int bb = t; bb < NB; bb += 256) {
            while (cnt[bb] - flushed[bb] >= 8) {
                int gpos = atomicAdd(&cur2[x * NB + bb], 8);
                if (gpos + 8 <= CAPX) {
                    const int2* src = &bins[bb][flushed[bb] & (BIN_CAP - 1)];
                    int2* dst = &arena1[((size_t)x * NB + bb) * CAPX + gpos];
                    const int4* s4 = (const int4*)src;
                    int4* d4 = (int4*)dst;
                    d4[0] = s4[0]; d4[1] = s4[1]; d4[2] = s4[2]; d4[3] = s4[3];
                }
                flushed[bb] += 8;
            }
        }
        __syncthreads();
        r = rn; c = cn; v = vn;
    }
    for (int bb = t; bb < NB; bb += 256) {
        int rem = cnt[bb] - flushed[bb];
        if (rem > 0) {
            int gpos = atomicAdd(&cur2[x * NB + bb], rem);
            if (gpos + rem <= CAPX) {
                int2* dst = &arena1[((size_t)x * NB + bb) * CAPX + gpos];
                for (int k = 0; k < rem; ++k)
                    dst[k] = bins[bb][(flushed[bb] + k) & (BIN_CAP - 1)];
            }
        }
    }
}

// ---------------------------------------------------------------------------
// Bucket-local counting sort (proven): key = rl*NCG + (c>>13); arena2 record
// packed 4B: (bf16bits(v^2) << 17) | c. rowoff = (start,end) into arena2.
// ---------------------------------------------------------------------------
__global__ __launch_bounds__(256) void sort_bucket_kernel(
    const int* __restrict__ cur2, const int2* __restrict__ arena1,
    unsigned int* __restrict__ arena2, int2* __restrict__ rowoff,
    int nrows, int NB, int CAPX, int CAP)
{
    __shared__ int koff[KEYS];
    __shared__ int sscan[256];

    int b = blockIdx.x;
    int t = threadIdx.x;
    unsigned int* dst = arena2 + (size_t)b * CAP;

    for (int i = t; i < KEYS; i += 256) koff[i] = 0;
    __syncthreads();

    for (int x = 0; x < NXS; ++x) {
        int n_x = cur2[x * NB + b]; if (n_x > CAPX) n_x = CAPX;
        const int2* seg = arena1 + ((size_t)x * NB + b) * CAPX;
        for (int i = t; i < n_x; i += 256) {
            int rx = seg[i].x;
            int key = (rx >> 17) * NCG + ((rx & 0x1FFFF) >> 13);
            atomicAdd(&koff[key], 1);
        }
    }
    __syncthreads();

    const int PER = (KEYS + 255) / 256;
    int lo = t * PER, hi = lo + PER; if (hi > KEYS) hi = KEYS; if (lo > KEYS) lo = KEYS;
    int s = 0;
    for (int i = lo; i < hi; ++i) s += koff[i];
    sscan[t] = s;
    __syncthreads();
#pragma unroll
    for (int d = 1; d < 256; d <<= 1) {
        int u = (t >= d) ? sscan[t - d] : 0;
        __syncthreads();
        sscan[t] += u;
        __syncthreads();
    }
    int total = sscan[255];
    int run = (t == 0) ? 0 : sscan[t - 1];
    for (int i = lo; i < hi; ++i) {
        int c0 = koff[i];
        koff[i] = run;
        run += c0;
    }
    __syncthreads();

    if (t < RB) {
        int grow = b * RB + t;
        if (grow < nrows) {
            int start = koff[t * NCG];
            int end   = (t == RB - 1) ? total : koff[(t + 1) * NCG];
            rowoff[grow] = make_int2(b * CAP + start, b * CAP + end);
        }
    }
    __syncthreads();

    for (int x = 0; x < NXS; ++x) {
        int n_x = cur2[x * NB + b]; if (n_x > CAPX) n_x = CAPX;
        const int2* seg = arena1 + ((size_t)x * NB + b) * CAPX;
        for (int i = t; i < n_x; i += 256) {
            int2 rec = seg[i];
            int c = rec.x & 0x1FFFF;
            int key = (rec.x >> 17) * NCG + (c >> 13);
            int pos = atomicAdd(&koff[key], 1);
            unsigned int pk = ((unsigned int)f2bfbits(__int_as_float(rec.y)) << 17)
                              | (unsigned int)c;
            if (pos < CAP) dst[pos] = pk;
        }
    }
}

// ---------------------------------------------------------------------------
// One wave per row, 4-deep unrolled bf16 gather, register acc. Final
// multiply now reads the row's own bf16 wx from wxh (L2-hot, 256B) --
// the 51.2 MB f32 wxf read is eliminated. out written directly (no RMW).
// ---------------------------------------------------------------------------
__global__ __launch_bounds__(256) void agg_row_kernel(
    const int2* __restrict__ rowoff, const unsigned int* __restrict__ arena2,
    const unsigned int* __restrict__ wxh32, float* __restrict__ out,
    int nrows)
{
    int wid  = (blockIdx.x * 256 + threadIdx.x) >> 6;
    int lane = threadIdx.x & 63;
    if (wid >= nrows) return;

    int2 se   = rowoff[wid];
    int start = __builtin_amdgcn_readfirstlane(se.x);
    int end   = __builtin_amdgcn_readfirstlane(se.y);

    float accx = 0.f, accy = 0.f;
    int e = start;
    for (; e + 3 < end; e += 4) {
        unsigned int p0 = arena2[e];
        unsigned int p1 = arena2[e + 1];
        unsigned int p2 = arena2[e + 2];
        unsigned int p3 = arena2[e + 3];
        unsigned int g0 = wxh32[(size_t)(p0 & 0x1FFFF) * 64 + lane];
        unsigned int g1 = wxh32[(size_t)(p1 & 0x1FFFF) * 64 + lane];
        unsigned int g2 = wxh32[(size_t)(p2 & 0x1FFFF) * 64 + lane];
        unsigned int g3 = wxh32[(size_t)(p3 & 0x1FFFF) * 64 + lane];
        float v0 = __uint_as_float((p0 >> 17) << 16);
        float v1 = __uint_as_float((p1 >> 17) << 16);
        float v2 = __uint_as_float((p2 >> 17) << 16);
        float v3 = __uint_as_float((p3 >> 17) << 16);
        accx = fmaf(v0, __uint_as_float(g0 << 16), accx);
        accy = fmaf(v0, __uint_as_float(g0 & 0xFFFF0000u), accy);
        accx = fmaf(v1, __uint_as_float(g1 << 16), accx);
        accy = fmaf(v1, __uint_as_float(g1 & 0xFFFF0000u), accy);
        accx = fmaf(v2, __uint_as_float(g2 << 16), accx);
        accy = fmaf(v2, __uint_as_float(g2 & 0xFFFF0000u), accy);
        accx = fmaf(v3, __uint_as_float(g3 << 16), accx);
        accy = fmaf(v3, __uint_as_float(g3 & 0xFFFF0000u), accy);
    }
    for (; e < end; ++e) {
        unsigned int p0 = arena2[e];
        unsigned int g0 = wxh32[(size_t)(p0 & 0x1FFFF) * 64 + lane];
        float v0 = __uint_as_float((p0 >> 17) << 16);
        accx = fmaf(v0, __uint_as_float(g0 << 16), accx);
        accy = fmaf(v0, __uint_as_float(g0 & 0xFFFF0000u), accy);
    }

    // final multiply from the row's own bf16 wx (no f32 wxf read)
    unsigned int gw = wxh32[(size_t)wid * 64 + lane];
    float2 o;
    o.x = __uint_as_float(gw << 16) * accx;
    o.y = __uint_as_float(gw & 0xFFFF0000u) * accy;
    *reinterpret_cast<float2*>(out + (size_t)wid * F + lane * 2) = o;
}

// ---------------------------------------------------------------------------
// Last-resort fallback (round-1, proven): atomic scatter + finalize
// ---------------------------------------------------------------------------
__global__ __launch_bounds__(256) void edge_scatter_kernel(
    const int* __restrict__ rowi, const int* __restrict__ coli,
    const float* __restrict__ ev, const float* __restrict__ wx,
    float* __restrict__ temp, int E)
{
    int tid = blockIdx.x * 256 + threadIdx.x;
    int e   = tid >> 5;
    if (e >= E) return;
    int lane = tid & 31;
    int r = rowi[e];
    int c = coli[e];
    if (r == c) return;
    float v = ev[e];
    v = v * v;
    const float4 wv = *reinterpret_cast<const float4*>(wx + (size_t)c * F + lane * 4);
    float* tp = temp + (size_t)r * F + lane * 4;
    atomicAdd(tp + 0, v * wv.x);
    atomicAdd(tp + 1, v * wv.y);
    atomicAdd(tp + 2, v * wv.z);
    atomicAdd(tp + 3, v * wv.w);
}

__global__ __launch_bounds__(256) void finalize_kernel(
    float* __restrict__ out, const float* __restrict__ temp, int n4)
{
    int i = blockIdx.x * 256 + threadIdx.x;
    if (i >= n4) return;
    float4 o  = reinterpret_cast<float4*>(out)[i];
    float4 tv = reinterpret_cast<const float4*>(temp)[i];
    o.x *= tv.x; o.y *= tv.y; o.z *= tv.z; o.w *= tv.w;
    reinterpret_cast<float4*>(out)[i] = o;
}

__global__ void Interaction_GraphConvolution_55963423867450_kernel() {}

extern "C" void kernel_launch(void* const* d_in, const int* in_sizes, int n_in,
                              void* d_out, int out_size, void* d_ws, size_t ws_size,
                              hipStream_t stream)
{
    const float* X  = (const float*)d_in[0];
    const int*   ei = (const int*)d_in[1];   // [2, E] int32
    const float* ev = (const float*)d_in[2];
    const float* W  = (const float*)d_in[3];
    const float* b  = (const float*)d_in[4];
    float* out = (float*)d_out;

    int nrows = in_sizes[0] / F;
    int E     = in_sizes[2];
    const int* rowi = ei;
    const int* coli = ei + E;

    int gblocks = (int)((nrows + 127) / 128);

    int NB = (nrows + RB - 1) / RB;
    if (NB <= NB_MAX && nrows < (1 << 17)) {
        long avg = (long)E / NB;                                 // records per bucket
        int CAP  = (int)(((avg * 9) / 8 + 192 + 7) & ~7L);       // arena2 per-bucket
        int CAPX = (int)(((avg / NXS) * 5 / 4 + 64 + 7) & ~7L);  // per (x,bucket) segment

        char* p = (char*)d_ws;
        __hip_bfloat16* wxh = (__hip_bfloat16*)p;
        p += (size_t)nrows * F * sizeof(__hip_bfloat16);
        int* cur2 = (int*)p;
        p += (size_t)NXS * NB * sizeof(int);
        p = (char*)(((uintptr_t)p + 63) & ~(uintptr_t)63);
        int2* rowoff = (int2*)p;
        p += (size_t)nrows * sizeof(int2);
        int2* arena1 = (int2*)p;
        p += (size_t)NXS * NB * CAPX * sizeof(int2);
        unsigned int* arena2 = (unsigned int*)p;
        p += (size_t)NB * CAP * sizeof(unsigned int);
        size_t need = (size_t)(p - (char*)d_ws);

        if (ws_size >= need) {
            hipMemsetAsync(cur2, 0, (size_t)NXS * NB * sizeof(int), stream);
            gemm_mfma_kernel<<<gblocks, 256, 0, stream>>>(X, W, b, out, wxh, nrows, 0);
            bin_edges_kernel<<<NBLK_BIN, 256, 0, stream>>>(rowi, coli, ev, cur2,
                                                           arena1, E, NB, CAPX);
            sort_bucket_kernel<<<NB, 256, 0, stream>>>(cur2, arena1, arena2,
                                                       rowoff, nrows, NB, CAPX, CAP);
            int ablocks = (int)(((long)nrows * 64 + 255) / 256);
            agg_row_kernel<<<ablocks, 256, 0, stream>>>(rowoff, arena2,
                                                        (const unsigned int*)wxh,
                                                        out, nrows);
            return;
        }
    }

    // ---------- last resort: atomic scatter (round-1) ----------
    float* temp = (float*)d_ws;   // [nrows, 128]
    hipMemsetAsync(temp, 0, (size_t)nrows * F * sizeof(float), stream);
    __hip_bfloat16* wxh_dummy = (__hip_bfloat16*)((char*)d_ws + (size_t)nrows * F * sizeof(float));
    gemm_mfma_kernel<<<(int)((nrows + 127) / 128), 256, 0, stream>>>(X, W, b, out, wxh_dummy, nrows, 1);
    long ethreads = (long)E * 32;
    int  eblocks32 = (int)((ethreads + 255) / 256);
    edge_scatter_kernel<<<eblocks32, 256, 0, stream>>>(rowi, coli, ev, out, temp, E);
    int n4 = nrows * F / 4;
    finalize_kernel<<<(n4 + 255) / 256, 256, 0, stream>>>(out, temp, n4);
}

// Round 11
// 214.153 us; speedup vs baseline: 11.3133x; 1.0085x over previous
//
#include <hip/hip_runtime.h>
#include <hip/hip_bf16.h>

#define F 128
#define RB 196            // rows per bucket
#define NB_MAX 511        // max buckets (nrows <= 100156)
#define BIN_CAP 16        // LDS records per bin (circular)
#define NBLK_BIN 512      // bin_edges grid (2 blocks/CU)
#define NXS 16            // cursor/arena sub-segments (atomic de-contention)
#define NCG 16            // column groups (c >> 13) for gather locality
#define KEYS (RB * NCG)   // 3136 sort keys per bucket

typedef __attribute__((ext_vector_type(8))) short bf16x8;
typedef __attribute__((ext_vector_type(4))) float f32x4;

static __device__ __forceinline__ unsigned short f2bfbits(float f) {
    __hip_bfloat16 h = __float2bfloat16(f);
    return __builtin_bit_cast(unsigned short, h);
}
static __device__ __forceinline__ short f2bf(float f) {
    __hip_bfloat16 h = __float2bfloat16(f);
    return __builtin_bit_cast(short, h);
}

// ---------------------------------------------------------------------------
// MFMA GEMM (proven): wx = X @ W.T + b, 128x128 tile, K=128.
// Main path: writes ONLY bf16 wxh (25.6 MB). Fallback: also f32 wxf.
// ---------------------------------------------------------------------------
__global__ __launch_bounds__(256) void gemm_mfma_kernel(
    const float* __restrict__ X, const float* __restrict__ W,
    const float* __restrict__ bias, float* __restrict__ wxf,
    __hip_bfloat16* __restrict__ wxh, int nrows, int writeF)
{
    __shared__ short xs[128][136];
    __shared__ short wt[128][136];
    __shared__ float bsh[128];

    int t = threadIdx.x;
    long row0 = (long)blockIdx.x * 128;

    {
        int r = t >> 1, h = t & 1;
        const float4* src = reinterpret_cast<const float4*>(W + r * F + h * 64);
#pragma unroll
        for (int i = 0; i < 16; ++i) {
            float4 v = src[i];
            short4 s;
            s.x = f2bf(v.x); s.y = f2bf(v.y); s.z = f2bf(v.z); s.w = f2bf(v.w);
            *reinterpret_cast<short4*>(&wt[r][h * 64 + i * 4]) = s;
        }
        if (t < 128) bsh[t] = bias[t];
    }
    {
        int r = t >> 1, h = t & 1;
        long gr = row0 + r; if (gr > nrows - 1) gr = nrows - 1;
        const float4* src = reinterpret_cast<const float4*>(X + gr * F + h * 64);
#pragma unroll
        for (int i = 0; i < 16; ++i) {
            float4 v = src[i];
            short4 s;
            s.x = f2bf(v.x); s.y = f2bf(v.y); s.z = f2bf(v.z); s.w = f2bf(v.w);
            *reinterpret_cast<short4*>(&xs[r][h * 64 + i * 4]) = s;
        }
    }
    __syncthreads();

    int wave = t >> 6, lane = t & 63;
    int l15 = lane & 15, lg = lane >> 4;
    int mrow = wave * 32;

    float bj[8];
#pragma unroll
    for (int nf = 0; nf < 8; ++nf) bj[nf] = bsh[nf * 16 + l15];

    f32x4 acc[2][8] = {};

#pragma unroll
    for (int ks = 0; ks < 4; ++ks) {
        bf16x8 a0 = *reinterpret_cast<const bf16x8*>(&xs[mrow + l15][ks * 32 + lg * 8]);
        bf16x8 a1 = *reinterpret_cast<const bf16x8*>(&xs[mrow + 16 + l15][ks * 32 + lg * 8]);
#pragma unroll
        for (int nf = 0; nf < 8; ++nf) {
            bf16x8 bfr = *reinterpret_cast<const bf16x8*>(&wt[nf * 16 + l15][ks * 32 + lg * 8]);
            acc[0][nf] = __builtin_amdgcn_mfma_f32_16x16x32_bf16(a0, bfr, acc[0][nf], 0, 0, 0);
            acc[1][nf] = __builtin_amdgcn_mfma_f32_16x16x32_bf16(a1, bfr, acc[1][nf], 0, 0, 0);
        }
    }

#pragma unroll
    for (int mf = 0; mf < 2; ++mf) {
#pragma unroll
        for (int i = 0; i < 4; ++i) {
            long grow = row0 + mrow + mf * 16 + lg * 4 + i;
            if (grow < nrows) {
#pragma unroll
                for (int nf = 0; nf < 8; ++nf) {
                    float v = acc[mf][nf][i] + bj[nf];
                    int col = nf * 16 + l15;
                    wxh[grow * F + col] = __float2bfloat16(v);
                    if (writeF) wxf[grow * F + col] = v;
                }
            }
        }
    }
}

// ---------------------------------------------------------------------------
// Counting-bin (proven): LDS write-combining + 16-way split cursors/arenas
// + prefetch. arena1 record = (rl<<17 | c, v^2 f32); diagonal v^2 = 0.
// ---------------------------------------------------------------------------
__global__ __launch_bounds__(256) void bin_edges_kernel(
    const int* __restrict__ rowi, const int* __restrict__ coli,
    const float* __restrict__ ev, int* __restrict__ cur2,
    int2* __restrict__ arena1, int E, int NB, int CAPX)
{
    __shared__ int2 bins[NB_MAX][BIN_CAP];
    __shared__ int  cnt[NB_MAX];
    __shared__ int  flushed[NB_MAX];

    int t = threadIdx.x;
    int x = blockIdx.x & (NXS - 1);
    for (int i = t; i < NB; i += 256) { cnt[i] = 0; flushed[i] = 0; }
    __syncthreads();

    long per   = ((long)E + NBLK_BIN - 1) / NBLK_BIN;
    long start = (long)blockIdx.x * per;
    long endE  = start + per; if (endE > E) endE = E;

    int r = 0, c = 0; float v = 0.f;
    {
        long i0 = start + t;
        if (i0 < endE) { r = rowi[i0]; c = coli[i0]; v = ev[i0]; }
    }

    for (long base = start; base < endE; base += 256) {
        if (base + t < endE) {
            float v2 = (r != c) ? v * v : 0.0f;
            int b  = r / RB;
            int rl = r - b * RB;
            int pos = atomicAdd(&cnt[b], 1);
            bins[b][pos & (BIN_CAP - 1)] = make_int2((rl << 17) | c, __float_as_int(v2));
        }
        int rn = 0, cn = 0; float vn = 0.f;
        {
            long i2 = base + 256 + t;
            if (i2 < endE) { rn = rowi[i2]; cn = coli[i2]; vn = ev[i2]; }
        }
        __syncthreads();
        for (int bb = t; bb < NB; bb += 256) {
            while (cnt[bb] - flushed[bb] >= 8) {
                int gpos = atomicAdd(&cur2[x * NB + bb], 8);
                if (gpos + 8 <= CAPX) {
                    const int2* src = &bins[bb][flushed[bb] & (BIN_CAP - 1)];
                    int2* dst = &arena1[((size_t)x * NB + bb) * CAPX + gpos];
                    const int4* s4 = (const int4*)src;
                    int4* d4 = (int4*)dst;
                    d4[0] = s4[0]; d4[1] = s4[1]; d4[2] = s4[2]; d4[3] = s4[3];
                }
                flushed[bb] += 8;
            }
        }
        __syncthreads();
        r = rn; c = cn; v = vn;
    }
    for (int bb = t; bb < NB; bb += 256) {
        int rem = cnt[bb] - flushed[bb];
        if (rem > 0) {
            int gpos = atomicAdd(&cur2[x * NB + bb], rem);
            if (gpos + rem <= CAPX) {
                int2* dst = &arena1[((size_t)x * NB + bb) * CAPX + gpos];
                for (int k = 0; k < rem; ++k)
                    dst[k] = bins[bb][(flushed[bb] + k) & (BIN_CAP - 1)];
            }
        }
    }
}

// ---------------------------------------------------------------------------
// Bucket-local counting sort (proven): key = rl*NCG + (c>>13); arena2 record
// packed 4B: (bf16bits(v^2) << 17) | c. rowoff = (start,end) into arena2.
// ---------------------------------------------------------------------------
__global__ __launch_bounds__(256) void sort_bucket_kernel(
    const int* __restrict__ cur2, const int2* __restrict__ arena1,
    unsigned int* __restrict__ arena2, int2* __restrict__ rowoff,
    int nrows, int NB, int CAPX, int CAP)
{
    __shared__ int koff[KEYS];
    __shared__ int sscan[256];

    int b = blockIdx.x;
    int t = threadIdx.x;
    unsigned int* dst = arena2 + (size_t)b * CAP;

    for (int i = t; i < KEYS; i += 256) koff[i] = 0;
    __syncthreads();

    for (int x = 0; x < NXS; ++x) {
        int n_x = cur2[x * NB + b]; if (n_x > CAPX) n_x = CAPX;
        const int2* seg = arena1 + ((size_t)x * NB + b) * CAPX;
        for (int i = t; i < n_x; i += 256) {
            int rx = seg[i].x;
            int key = (rx >> 17) * NCG + ((rx & 0x1FFFF) >> 13);
            atomicAdd(&koff[key], 1);
        }
    }
    __syncthreads();

    const int PER = (KEYS + 255) / 256;
    int lo = t * PER, hi = lo + PER; if (hi > KEYS) hi = KEYS; if (lo > KEYS) lo = KEYS;
    int s = 0;
    for (int i = lo; i < hi; ++i) s += koff[i];
    sscan[t] = s;
    __syncthreads();
#pragma unroll
    for (int d = 1; d < 256; d <<= 1) {
        int u = (t >= d) ? sscan[t - d] : 0;
        __syncthreads();
        sscan[t] += u;
        __syncthreads();
    }
    int total = sscan[255];
    int run = (t == 0) ? 0 : sscan[t - 1];
    for (int i = lo; i < hi; ++i) {
        int c0 = koff[i];
        koff[i] = run;
        run += c0;
    }
    __syncthreads();

    if (t < RB) {
        int grow = b * RB + t;
        if (grow < nrows) {
            int start = koff[t * NCG];
            int end   = (t == RB - 1) ? total : koff[(t + 1) * NCG];
            rowoff[grow] = make_int2(b * CAP + start, b * CAP + end);
        }
    }
    __syncthreads();

    for (int x = 0; x < NXS; ++x) {
        int n_x = cur2[x * NB + b]; if (n_x > CAPX) n_x = CAPX;
        const int2* seg = arena1 + ((size_t)x * NB + b) * CAPX;
        for (int i = t; i < n_x; i += 256) {
            int2 rec = seg[i];
            int c = rec.x & 0x1FFFF;
            int key = (rec.x >> 17) * NCG + (c >> 13);
            int pos = atomicAdd(&koff[key], 1);
            unsigned int pk = ((unsigned int)f2bfbits(__int_as_float(rec.y)) << 17)
                              | (unsigned int)c;
            if (pos < CAP) dst[pos] = pk;
        }
    }
}

// ---------------------------------------------------------------------------
// One wave per row. v2: explicit 8-deep load/gather/fma phases so >=8
// gathers stay in flight per wave (round-10 showed VGPR=8 => compiler had
// serialized the loads; this is MLP-bound, not BW-bound). Self-row wxh
// read hoisted above the loop. out = bf16(wx) * acc, written directly.
// ---------------------------------------------------------------------------
__global__ __launch_bounds__(256) void agg_row_kernel(
    const int2* __restrict__ rowoff, const unsigned int* __restrict__ arena2,
    const unsigned int* __restrict__ wxh32, float* __restrict__ out,
    int nrows)
{
    int wid  = (blockIdx.x * 256 + threadIdx.x) >> 6;
    int lane = threadIdx.x & 63;
    if (wid >= nrows) return;

    int2 se   = rowoff[wid];
    int start = __builtin_amdgcn_readfirstlane(se.x);
    int end   = __builtin_amdgcn_readfirstlane(se.y);

    unsigned int gw = wxh32[(size_t)wid * 64 + lane];   // self row, hoisted
    const unsigned int* wl = wxh32 + lane;

    float accx = 0.f, accy = 0.f;
    int e = start;
    for (; e + 7 < end; e += 8) {
        unsigned int p0 = arena2[e];
        unsigned int p1 = arena2[e + 1];
        unsigned int p2 = arena2[e + 2];
        unsigned int p3 = arena2[e + 3];
        unsigned int p4 = arena2[e + 4];
        unsigned int p5 = arena2[e + 5];
        unsigned int p6 = arena2[e + 6];
        unsigned int p7 = arena2[e + 7];
        unsigned int g0 = wl[(size_t)(p0 & 0x1FFFF) * 64];
        unsigned int g1 = wl[(size_t)(p1 & 0x1FFFF) * 64];
        unsigned int g2 = wl[(size_t)(p2 & 0x1FFFF) * 64];
        unsigned int g3 = wl[(size_t)(p3 & 0x1FFFF) * 64];
        unsigned int g4 = wl[(size_t)(p4 & 0x1FFFF) * 64];
        unsigned int g5 = wl[(size_t)(p5 & 0x1FFFF) * 64];
        unsigned int g6 = wl[(size_t)(p6 & 0x1FFFF) * 64];
        unsigned int g7 = wl[(size_t)(p7 & 0x1FFFF) * 64];
        float v0 = __uint_as_float((p0 >> 17) << 16);
        float v1 = __uint_as_float((p1 >> 17) << 16);
        float v2 = __uint_as_float((p2 >> 17) << 16);
        float v3 = __uint_as_float((p3 >> 17) << 16);
        float v4 = __uint_as_float((p4 >> 17) << 16);
        float v5 = __uint_as_float((p5 >> 17) << 16);
        float v6 = __uint_as_float((p6 >> 17) << 16);
        float v7 = __uint_as_float((p7 >> 17) << 16);
        accx = fmaf(v0, __uint_as_float(g0 << 16), accx);
        accy = fmaf(v0, __uint_as_float(g0 & 0xFFFF0000u), accy);
        accx = fmaf(v1, __uint_as_float(g1 << 16), accx);
        accy = fmaf(v1, __uint_as_float(g1 & 0xFFFF0000u), accy);
        accx = fmaf(v2, __uint_as_float(g2 << 16), accx);
        accy = fmaf(v2, __uint_as_float(g2 & 0xFFFF0000u), accy);
        accx = fmaf(v3, __uint_as_float(g3 << 16), accx);
        accy = fmaf(v3, __uint_as_float(g3 & 0xFFFF0000u), accy);
        accx = fmaf(v4, __uint_as_float(g4 << 16), accx);
        accy = fmaf(v4, __uint_as_float(g4 & 0xFFFF0000u), accy);
        accx = fmaf(v5, __uint_as_float(g5 << 16), accx);
        accy = fmaf(v5, __uint_as_float(g5 & 0xFFFF0000u), accy);
        accx = fmaf(v6, __uint_as_float(g6 << 16), accx);
        accy = fmaf(v6, __uint_as_float(g6 & 0xFFFF0000u), accy);
        accx = fmaf(v7, __uint_as_float(g7 << 16), accx);
        accy = fmaf(v7, __uint_as_float(g7 & 0xFFFF0000u), accy);
    }
    for (; e < end; ++e) {
        unsigned int p0 = arena2[e];
        unsigned int g0 = wl[(size_t)(p0 & 0x1FFFF) * 64];
        float v0 = __uint_as_float((p0 >> 17) << 16);
        accx = fmaf(v0, __uint_as_float(g0 << 16), accx);
        accy = fmaf(v0, __uint_as_float(g0 & 0xFFFF0000u), accy);
    }

    float2 o;
    o.x = __uint_as_float(gw << 16) * accx;
    o.y = __uint_as_float(gw & 0xFFFF0000u) * accy;
    *reinterpret_cast<float2*>(out + (size_t)wid * F + lane * 2) = o;
}

// ---------------------------------------------------------------------------
// Last-resort fallback (round-1, proven): atomic scatter + finalize
// ---------------------------------------------------------------------------
__global__ __launch_bounds__(256) void edge_scatter_kernel(
    const int* __restrict__ rowi, const int* __restrict__ coli,
    const float* __restrict__ ev, const float* __restrict__ wx,
    float* __restrict__ temp, int E)
{
    int tid = blockIdx.x * 256 + threadIdx.x;
    int e   = tid >> 5;
    if (e >= E) return;
    int lane = tid & 31;
    int r = rowi[e];
    int c = coli[e];
    if (r == c) return;
    float v = ev[e];
    v = v * v;
    const float4 wv = *reinterpret_cast<const float4*>(wx + (size_t)c * F + lane * 4);
    float* tp = temp + (size_t)r * F + lane * 4;
    atomicAdd(tp + 0, v * wv.x);
    atomicAdd(tp + 1, v * wv.y);
    atomicAdd(tp + 2, v * wv.z);
    atomicAdd(tp + 3, v * wv.w);
}

__global__ __launch_bounds__(256) void finalize_kernel(
    float* __restrict__ out, const float* __restrict__ temp, int n4)
{
    int i = blockIdx.x * 256 + threadIdx.x;
    if (i >= n4) return;
    float4 o  = reinterpret_cast<float4*>(out)[i];
    float4 tv = reinterpret_cast<const float4*>(temp)[i];
    o.x *= tv.x; o.y *= tv.y; o.z *= tv.z; o.w *= tv.w;
    reinterpret_cast<float4*>(out)[i] = o;
}

__global__ void Interaction_GraphConvolution_55963423867450_kernel() {}

extern "C" void kernel_launch(void* const* d_in, const int* in_sizes, int n_in,
                              void* d_out, int out_size, void* d_ws, size_t ws_size,
                              hipStream_t stream)
{
    const float* X  = (const float*)d_in[0];
    const int*   ei = (const int*)d_in[1];   // [2, E] int32
    const float* ev = (const float*)d_in[2];
    const float* W  = (const float*)d_in[3];
    const float* b  = (const float*)d_in[4];
    float* out = (float*)d_out;

    int nrows = in_sizes[0] / F;
    int E     = in_sizes[2];
    const int* rowi = ei;
    const int* coli = ei + E;

    int gblocks = (int)((nrows + 127) / 128);

    int NB = (nrows + RB - 1) / RB;
    if (NB <= NB_MAX && nrows < (1 << 17)) {
        long avg = (long)E / NB;                                 // records per bucket
        int CAP  = (int)(((avg * 9) / 8 + 192 + 7) & ~7L);       // arena2 per-bucket
        int CAPX = (int)(((avg / NXS) * 5 / 4 + 64 + 7) & ~7L);  // per (x,bucket) segment

        char* p = (char*)d_ws;
        __hip_bfloat16* wxh = (__hip_bfloat16*)p;
        p += (size_t)nrows * F * sizeof(__hip_bfloat16);
        int* cur2 = (int*)p;
        p += (size_t)NXS * NB * sizeof(int);
        p = (char*)(((uintptr_t)p + 63) & ~(uintptr_t)63);
        int2* rowoff = (int2*)p;
        p += (size_t)nrows * sizeof(int2);
        int2* arena1 = (int2*)p;
        p += (size_t)NXS * NB * CAPX * sizeof(int2);
        unsigned int* arena2 = (unsigned int*)p;
        p += (size_t)NB * CAP * sizeof(unsigned int);
        size_t need = (size_t)(p - (char*)d_ws);

        if (ws_size >= need) {
            hipMemsetAsync(cur2, 0, (size_t)NXS * NB * sizeof(int), stream);
            gemm_mfma_kernel<<<gblocks, 256, 0, stream>>>(X, W, b, out, wxh, nrows, 0);
            bin_edges_kernel<<<NBLK_BIN, 256, 0, stream>>>(rowi, coli, ev, cur2,
                                                           arena1, E, NB, CAPX);
            sort_bucket_kernel<<<NB, 256, 0, stream>>>(cur2, arena1, arena2,
                                                       rowoff, nrows, NB, CAPX, CAP);
            int ablocks = (int)(((long)nrows * 64 + 255) / 256);
            agg_row_kernel<<<ablocks, 256, 0, stream>>>(rowoff, arena2,
                                                        (const unsigned int*)wxh,
                                                        out, nrows);
            return;
        }
    }

    // ---------- last resort: atomic scatter (round-1) ----------
    float* temp = (float*)d_ws;   // [nrows, 128]
    hipMemsetAsync(temp, 0, (size_t)nrows * F * sizeof(float), stream);
    __hip_bfloat16* wxh_dummy = (__hip_bfloat16*)((char*)d_ws + (size_t)nrows * F * sizeof(float));
    gemm_mfma_kernel<<<(int)((nrows + 127) / 128), 256, 0, stream>>>(X, W, b, out, wxh_dummy, nrows, 1);
    long ethreads = (long)E * 32;
    int  eblocks32 = (int)((ethreads + 255) / 256);
    edge_scatter_kernel<<<eblocks32, 256, 0, stream>>>(rowi, coli, ev, out, temp, E);
    int n4 = nrows * F / 4;
    finalize_kernel<<<(n4 + 255) / 256, 256, 0, stream>>>(out, temp, n4);
}